// Round 1
// baseline (1519.947 us; speedup 1.0000x reference)
//
#include <hip/hip_runtime.h>

// GCN 2-layer: out = relu(Ahat * relu(Ahat * (x@W1) + b1) @ W2 + b2)
// Ahat = D^-1/2 (A+I) D^-1/2.  Trick: g = (X@W) * dis[row]; then
// agg[i] = dis[i] * (g[i] + sum_{dst=i} g[src]), so self-loop = acc init.

#define HID 128

__global__ void deg_kernel(const int* __restrict__ dst, float* __restrict__ deg, int E) {
    int i = blockIdx.x * blockDim.x + threadIdx.x;
    if (i < E) atomicAdd(&deg[dst[i]], 1.0f);
}

__global__ void dis_kernel(const float* __restrict__ deg, float* __restrict__ dis, int N) {
    int i = blockIdx.x * blockDim.x + threadIdx.x;
    if (i < N) dis[i] = rsqrtf(1.0f + deg[i]);
}

// One block handles 32 node-rows. W (K x 128) staged in LDS, X rows staged
// transposed in LDS. Thread (colq = tid&31, nodeq = tid>>5) computes a 4x4
// micro-tile: nodes nodeq*4..+3, cols colq*4..+3 -> 16 FMAs per 2 ds_read_b128.
template<int K>
__global__ __launch_bounds__(256, 2) void gemm_scale_kernel(
    const float* __restrict__ X, const float* __restrict__ W,
    const float* __restrict__ dis, float* __restrict__ g,
    float* __restrict__ acc, int N)
{
    __shared__ float Ws[K * HID];
    __shared__ float xs[K][32];
    const int tid = threadIdx.x;

    for (int i = tid; i < K * HID; i += 256) Ws[i] = W[i];

    const int node0 = blockIdx.x * 32;
    {
        const int nd = tid & 31;          // which of the 32 nodes
        const int gn = node0 + nd;
        const bool ok = gn < N;
        for (int k = tid >> 5; k < K; k += 8)
            xs[k][nd] = ok ? X[(size_t)gn * K + k] : 0.0f;  // LDS banks 0..31, conflict-free
    }
    __syncthreads();

    const int colq  = tid & 31;   // col  = colq*4
    const int nodeq = tid >> 5;   // node = nodeq*4 .. +3

    float a[4][4];
#pragma unroll
    for (int n = 0; n < 4; ++n)
#pragma unroll
        for (int c = 0; c < 4; ++c) a[n][c] = 0.0f;

    for (int k = 0; k < K; ++k) {
        float4 wv = *(const float4*)&Ws[k * HID + colq * 4];
        float4 xv = *(const float4*)&xs[k][nodeq * 4];  // broadcast within half-wave
        float xn[4] = {xv.x, xv.y, xv.z, xv.w};
        float wc[4] = {wv.x, wv.y, wv.z, wv.w};
#pragma unroll
        for (int n = 0; n < 4; ++n)
#pragma unroll
            for (int c = 0; c < 4; ++c)
                a[n][c] = fmaf(xn[n], wc[c], a[n][c]);
    }

#pragma unroll
    for (int n = 0; n < 4; ++n) {
        int node = node0 + nodeq * 4 + n;
        if (node < N) {
            float d = dis[node];
            float4 r;
            r.x = a[n][0] * d; r.y = a[n][1] * d;
            r.z = a[n][2] * d; r.w = a[n][3] * d;
            *(float4*)&g[(size_t)node * HID + colq * 4]   = r;
            *(float4*)&acc[(size_t)node * HID + colq * 4] = r;  // self-loop init
        }
    }
}

// One wave per edge: lane handles 2 consecutive floats of the 128-float row.
__global__ __launch_bounds__(256) void scatter_kernel(
    const float* __restrict__ g, float* __restrict__ acc,
    const int* __restrict__ src, const int* __restrict__ dst, int E)
{
    int e = blockIdx.x * 4 + (threadIdx.x >> 6);
    if (e >= E) return;
    int lane = threadIdx.x & 63;
    int s = src[e];
    int d = dst[e];
    float2 v = *(const float2*)&g[(size_t)s * HID + lane * 2];
    float* p = &acc[(size_t)d * HID + lane * 2];
    atomicAdd(p,     v.x);
    atomicAdd(p + 1, v.y);
}

__global__ void finalize_kernel(const float* __restrict__ acc,
    const float* __restrict__ dis, const float* __restrict__ b,
    float* __restrict__ out, int N)
{
    int t = blockIdx.x * blockDim.x + threadIdx.x;
    if (t < N * (HID / 4)) {
        int node = t >> 5;
        int c4 = (t & 31) * 4;
        float d = dis[node];
        float4 a  = *(const float4*)&acc[(size_t)node * HID + c4];
        float4 bb = *(const float4*)&b[c4];
        float4 r;
        r.x = fmaxf(fmaf(a.x, d, bb.x), 0.0f);
        r.y = fmaxf(fmaf(a.y, d, bb.y), 0.0f);
        r.z = fmaxf(fmaf(a.z, d, bb.z), 0.0f);
        r.w = fmaxf(fmaf(a.w, d, bb.w), 0.0f);
        *(float4*)&out[(size_t)node * HID + c4] = r;
    }
}

__global__ void edge_copy_kernel(const int* __restrict__ e, float* __restrict__ out, int n) {
    int i = blockIdx.x * blockDim.x + threadIdx.x;
    if (i < n) out[i] = (float)e[i];
}

extern "C" void kernel_launch(void* const* d_in, const int* in_sizes, int n_in,
                              void* d_out, int out_size, void* d_ws, size_t ws_size,
                              hipStream_t stream) {
    const float* x  = (const float*)d_in[0];
    const int*   ei = (const int*)d_in[1];   // int64 -> int32 by harness
    const float* W1 = (const float*)d_in[2];
    const float* b1 = (const float*)d_in[3];
    const float* W2 = (const float*)d_in[4];
    const float* b2 = (const float*)d_in[5];

    const int N = in_sizes[0] / 89;   // 50000
    const int E = in_sizes[1] / 2;    // 800000
    const int* src = ei;
    const int* dst = ei + E;

    float* out  = (float*)d_out;
    float* outH = out;                          // [N,128] h2
    float* outE = out + (size_t)N * HID;        // [2,E] edge_index as float

    // Workspace: deg[N], dis[N], A=g[N*128], B=acc[N*128]  (~51.6 MB)
    float* ws  = (float*)d_ws;
    float* deg = ws;
    float* dis = ws + N;
    float* A   = dis + N;
    float* B   = A + (size_t)N * HID;

    hipMemsetAsync(deg, 0, (size_t)N * sizeof(float), stream);
    deg_kernel<<<(E + 255) / 256, 256, 0, stream>>>(dst, deg, E);
    dis_kernel<<<(N + 255) / 256, 256, 0, stream>>>(deg, dis, N);

    const int gblocks = (N + 31) / 32;
    const int sblocks = (E + 3) / 4;
    const int fblocks = (N * (HID / 4) + 255) / 256;

    // Layer 1: h1 staged in d_out's h-region (fully overwritten later).
    gemm_scale_kernel<89><<<gblocks, 256, 0, stream>>>(x, W1, dis, A, B, N);
    scatter_kernel<<<sblocks, 256, 0, stream>>>(A, B, src, dst, E);
    finalize_kernel<<<fblocks, 256, 0, stream>>>(B, dis, b1, outH, N);

    // Layer 2
    gemm_scale_kernel<128><<<gblocks, 256, 0, stream>>>(outH, W2, dis, A, B, N);
    scatter_kernel<<<sblocks, 256, 0, stream>>>(A, B, src, dst, E);
    finalize_kernel<<<fblocks, 256, 0, stream>>>(B, dis, b2, outH, N);

    // Output 1: edge_index copied through as float.
    edge_copy_kernel<<<(2 * E + 255) / 256, 256, 0, stream>>>(ei, outE, 2 * E);
}

// Round 2
// 434.072 us; speedup vs baseline: 3.5016x; 3.5016x over previous
//
#include <hip/hip_runtime.h>

// GCN 2-layer. g = (X@W)*dis[row]; out = relu(dis*(g[node] + sum_{dst=node} g[src]) + b).
// Aggregation via CSR (by dst) gather -> no fp atomics, deterministic.

#define HID 128

__global__ void degi_kernel(const int* __restrict__ dst, int* __restrict__ deg, int E) {
    int i = blockIdx.x * blockDim.x + threadIdx.x;
    if (i < E) atomicAdd(&deg[dst[i]], 1);
}

__global__ void dis_kernel(const int* __restrict__ deg, float* __restrict__ dis, int N) {
    int i = blockIdx.x * blockDim.x + threadIdx.x;
    if (i < N) dis[i] = rsqrtf(1.0f + (float)deg[i]);
}

// Single-block exclusive scan: rowptr[0]=0, rowptr[i+1]=sum(deg[0..i]).
__global__ __launch_bounds__(1024) void scan_kernel(
    const int* __restrict__ deg, int* __restrict__ rowptr, int N)
{
    __shared__ int wsum[16];
    __shared__ int carry;
    const int tid = threadIdx.x;
    const int lane = tid & 63;
    const int wid = tid >> 6;
    if (tid == 0) carry = 0;
    __syncthreads();
    for (int base = 0; base < N; base += 1024) {
        int i = base + tid;
        int v = (i < N) ? deg[i] : 0;
        int s = v;
#pragma unroll
        for (int off = 1; off < 64; off <<= 1) {
            int t = __shfl_up(s, off, 64);
            if (lane >= off) s += t;
        }
        if (lane == 63) wsum[wid] = s;
        __syncthreads();
        if (wid == 0 && lane < 16) {
            int t = wsum[lane];
#pragma unroll
            for (int off = 1; off < 16; off <<= 1) {
                int u = __shfl_up(t, off, 64);
                if (lane >= off) t += u;
            }
            wsum[lane] = t;
        }
        __syncthreads();
        int waveoff = (wid == 0) ? 0 : wsum[wid - 1];
        int incl = carry + waveoff + s;
        if (i < N) rowptr[i + 1] = incl;
        __syncthreads();              // everyone has read carry
        if (tid == 1023) carry = incl;
        __syncthreads();
    }
    if (tid == 0) rowptr[0] = 0;
}

__global__ void csrfill_kernel(const int* __restrict__ src, const int* __restrict__ dst,
                               const int* __restrict__ rowptr, int* __restrict__ cursor,
                               int* __restrict__ csr, int E)
{
    int e = blockIdx.x * blockDim.x + threadIdx.x;
    if (e < E) {
        int d = dst[e];
        int pos = atomicAdd(&cursor[d], 1);
        csr[rowptr[d] + pos] = src[e];
    }
}

// One block handles 32 node-rows; 4x4 micro-tile per thread out of LDS.
template<int K>
__global__ __launch_bounds__(256, 2) void gemm_scale_kernel(
    const float* __restrict__ X, const float* __restrict__ W,
    const float* __restrict__ dis, float* __restrict__ g, int N)
{
    __shared__ float Ws[K * HID];
    __shared__ float xs[K][32];
    const int tid = threadIdx.x;

    for (int i = tid; i < K * HID; i += 256) Ws[i] = W[i];

    const int node0 = blockIdx.x * 32;
    {
        const int nd = tid & 31;
        const int gn = node0 + nd;
        const bool ok = gn < N;
        for (int k = tid >> 5; k < K; k += 8)
            xs[k][nd] = ok ? X[(size_t)gn * K + k] : 0.0f;
    }
    __syncthreads();

    const int colq  = tid & 31;
    const int nodeq = tid >> 5;

    float a[4][4];
#pragma unroll
    for (int n = 0; n < 4; ++n)
#pragma unroll
        for (int c = 0; c < 4; ++c) a[n][c] = 0.0f;

    for (int k = 0; k < K; ++k) {
        float4 wv = *(const float4*)&Ws[k * HID + colq * 4];
        float4 xv = *(const float4*)&xs[k][nodeq * 4];
        float xn[4] = {xv.x, xv.y, xv.z, xv.w};
        float wc[4] = {wv.x, wv.y, wv.z, wv.w};
#pragma unroll
        for (int n = 0; n < 4; ++n)
#pragma unroll
            for (int c = 0; c < 4; ++c)
                a[n][c] = fmaf(xn[n], wc[c], a[n][c]);
    }

#pragma unroll
    for (int n = 0; n < 4; ++n) {
        int node = node0 + nodeq * 4 + n;
        if (node < N) {
            float d = dis[node];
            float4 r;
            r.x = a[n][0] * d; r.y = a[n][1] * d;
            r.z = a[n][2] * d; r.w = a[n][3] * d;
            *(float4*)&g[(size_t)node * HID + colq * 4] = r;
        }
    }
}

// One wave per node: lane owns 2 floats of the row. CSR gather + fused
// dis*acc + bias + relu epilogue. 4-way unroll for load-latency ILP.
__global__ __launch_bounds__(256) void gather_kernel(
    const float* __restrict__ g, const int* __restrict__ rowptr,
    const int* __restrict__ csr, const float* __restrict__ dis,
    const float* __restrict__ b, float* __restrict__ out, int N)
{
    int node = blockIdx.x * 4 + (threadIdx.x >> 6);
    if (node >= N) return;
    int lane = threadIdx.x & 63;
    int beg = rowptr[node];
    int end = rowptr[node + 1];

    float2 acc = *(const float2*)&g[(size_t)node * HID + lane * 2];  // self loop
    int j = beg;
    for (; j + 4 <= end; j += 4) {
        int s0 = csr[j], s1 = csr[j + 1], s2 = csr[j + 2], s3 = csr[j + 3];
        float2 v0 = *(const float2*)&g[(size_t)s0 * HID + lane * 2];
        float2 v1 = *(const float2*)&g[(size_t)s1 * HID + lane * 2];
        float2 v2 = *(const float2*)&g[(size_t)s2 * HID + lane * 2];
        float2 v3 = *(const float2*)&g[(size_t)s3 * HID + lane * 2];
        acc.x += v0.x + v1.x + v2.x + v3.x;
        acc.y += v0.y + v1.y + v2.y + v3.y;
    }
    for (; j < end; ++j) {
        int s = csr[j];
        float2 v = *(const float2*)&g[(size_t)s * HID + lane * 2];
        acc.x += v.x; acc.y += v.y;
    }

    float d = dis[node];
    float2 bb = *(const float2*)&b[lane * 2];
    float2 r;
    r.x = fmaxf(fmaf(acc.x, d, bb.x), 0.0f);
    r.y = fmaxf(fmaf(acc.y, d, bb.y), 0.0f);
    *(float2*)&out[(size_t)node * HID + lane * 2] = r;
}

__global__ void edge_copy_kernel(const int* __restrict__ e, float* __restrict__ out, int n) {
    int i = blockIdx.x * blockDim.x + threadIdx.x;
    if (i < n) out[i] = (float)e[i];
}

extern "C" void kernel_launch(void* const* d_in, const int* in_sizes, int n_in,
                              void* d_out, int out_size, void* d_ws, size_t ws_size,
                              hipStream_t stream) {
    const float* x  = (const float*)d_in[0];
    const int*   ei = (const int*)d_in[1];
    const float* W1 = (const float*)d_in[2];
    const float* b1 = (const float*)d_in[3];
    const float* W2 = (const float*)d_in[4];
    const float* b2 = (const float*)d_in[5];

    const int N = in_sizes[0] / 89;   // 50000
    const int E = in_sizes[1] / 2;    // 800000
    const int* src = ei;
    const int* dst = ei + E;

    float* out  = (float*)d_out;
    float* outH = out;                      // [N,128] h2 (h1 staged here too)
    float* outE = out + (size_t)N * HID;    // [2,E] edge_index as float

    // Workspace layout (ints + floats):
    char* ws = (char*)d_ws;
    int*   degi   = (int*)ws;                         ws += (size_t)N * 4;
    int*   rowptr = (int*)ws;                         ws += (size_t)(N + 1) * 4;
    int*   cursor = (int*)ws;                         ws += (size_t)N * 4;
    int*   csr    = (int*)ws;                         ws += (size_t)E * 4;
    float* dis    = (float*)ws;                       ws += (size_t)N * 4;
    float* g      = (float*)ws;                       // N*128 floats

    hipMemsetAsync(degi,   0, (size_t)N * 4, stream);
    hipMemsetAsync(cursor, 0, (size_t)N * 4, stream);

    degi_kernel<<<(E + 255) / 256, 256, 0, stream>>>(dst, degi, E);
    dis_kernel<<<(N + 255) / 256, 256, 0, stream>>>(degi, dis, N);
    scan_kernel<<<1, 1024, 0, stream>>>(degi, rowptr, N);
    csrfill_kernel<<<(E + 255) / 256, 256, 0, stream>>>(src, dst, rowptr, cursor, csr, E);

    const int gblocks  = (N + 31) / 32;
    const int gtblocks = (N + 3) / 4;

    // Layer 1 (h1 staged in d_out's h-region, fully overwritten by layer 2)
    gemm_scale_kernel<89><<<gblocks, 256, 0, stream>>>(x, W1, dis, g, N);
    gather_kernel<<<gtblocks, 256, 0, stream>>>(g, rowptr, csr, dis, b1, outH, N);

    // Layer 2
    gemm_scale_kernel<128><<<gblocks, 256, 0, stream>>>(outH, W2, dis, g, N);
    gather_kernel<<<gtblocks, 256, 0, stream>>>(g, rowptr, csr, dis, b2, outH, N);

    edge_copy_kernel<<<(2 * E + 255) / 256, 256, 0, stream>>>(ei, outE, 2 * E);
}

// Round 3
// 377.372 us; speedup vs baseline: 4.0277x; 1.1502x over previous
//
#include <hip/hip_runtime.h>

// GCN 2-layer, restructured:
//   agg1[i] = dis_i*(dis_i*x_i + sum_{e:dst=i} dis_src*x_src)      (gather_x, 89 cols)
//   g2      = relu(agg1@W1 + b1) * dis_i                           (gemm, SCALE_OUT)
//   agg2[i] = dis_i*(g2_i + sum g2_src)                            (gather_h, 128 cols)
//   out     = relu(agg2@W2 + b2)                                   (gemm)
// CSR (by dst) gather -> no fp atomics, deterministic.

#define HID 128
#define KIN 89

__global__ void degi_kernel(const int* __restrict__ dst, int* __restrict__ deg, int E) {
    int i = blockIdx.x * blockDim.x + threadIdx.x;
    if (i < E) atomicAdd(&deg[dst[i]], 1);
}

// Phase A: per-block (1024 elems) sums of deg.
__global__ __launch_bounds__(1024) void scanA_kernel(
    const int* __restrict__ deg, int* __restrict__ bsum, int N)
{
    __shared__ int wsum[16];
    int tid = threadIdx.x, lane = tid & 63, wid = tid >> 6;
    int i = blockIdx.x * 1024 + tid;
    int v = (i < N) ? deg[i] : 0;
    int s = v;
#pragma unroll
    for (int off = 1; off < 64; off <<= 1) {
        int t = __shfl_up(s, off, 64);
        if (lane >= off) s += t;
    }
    if (lane == 63) wsum[wid] = s;
    __syncthreads();
    if (tid == 0) {
        int t = 0;
#pragma unroll
        for (int w = 0; w < 16; ++w) t += wsum[w];
        bsum[blockIdx.x] = t;
    }
}

// Phase B: exclusive scan of block sums (nb <= 64), one wave.
__global__ __launch_bounds__(64) void scanB_kernel(
    const int* __restrict__ bsum, int* __restrict__ boff, int nb)
{
    int lane = threadIdx.x;
    int v = (lane < nb) ? bsum[lane] : 0;
    int s = v;
#pragma unroll
    for (int off = 1; off < 64; off <<= 1) {
        int t = __shfl_up(s, off, 64);
        if (lane >= off) s += t;
    }
    if (lane < nb) boff[lane] = s - v;   // exclusive
}

// Phase C: full scan + write rowptr, cursor(=rowptr), dis.
__global__ __launch_bounds__(1024) void scanC_kernel(
    const int* __restrict__ deg, const int* __restrict__ boff,
    int* __restrict__ rowptr, int* __restrict__ cursor,
    float* __restrict__ dis, int N)
{
    __shared__ int wsum[16];
    int tid = threadIdx.x, lane = tid & 63, wid = tid >> 6;
    int i = blockIdx.x * 1024 + tid;
    int v = (i < N) ? deg[i] : 0;
    int s = v;
#pragma unroll
    for (int off = 1; off < 64; off <<= 1) {
        int t = __shfl_up(s, off, 64);
        if (lane >= off) s += t;
    }
    if (lane == 63) wsum[wid] = s;
    __syncthreads();
    if (wid == 0 && lane < 16) {
        int t = wsum[lane];
#pragma unroll
        for (int off = 1; off < 16; off <<= 1) {
            int u = __shfl_up(t, off, 16);
            if ((lane & 15) >= off) t += u;
        }
        wsum[lane] = t;
    }
    __syncthreads();
    int woff = wid ? wsum[wid - 1] : 0;
    int incl = boff[blockIdx.x] + woff + s;
    if (i < N) {
        rowptr[i + 1] = incl;
        cursor[i] = incl - v;
        dis[i] = rsqrtf(1.0f + (float)v);
    }
    if (i == 0) rowptr[0] = 0;
}

__global__ void csrfill_kernel(const int* __restrict__ src, const int* __restrict__ dst,
                               int* __restrict__ cursor, int* __restrict__ csr, int E)
{
    int e = blockIdx.x * blockDim.x + threadIdx.x;
    if (e < E) {
        int pos = atomicAdd(&cursor[dst[e]], 1);
        csr[pos] = src[e];
    }
}

// One wave per node over raw X (89 cols). Lane owns col lane (+ col lane+64 if <89).
__global__ __launch_bounds__(256) void gather_x_kernel(
    const float* __restrict__ X, const int* __restrict__ rowptr,
    const int* __restrict__ csr, const float* __restrict__ dis,
    float* __restrict__ agg, int N)
{
    int node = blockIdx.x * 4 + (threadIdx.x >> 6);
    if (node >= N) return;
    int lane = threadIdx.x & 63;
    bool hi = lane < (KIN - 64);
    float di = dis[node];
    const float* xr = X + (size_t)node * KIN;
    float a1 = di * xr[lane];
    float a2 = hi ? di * xr[lane + 64] : 0.0f;

    int beg = rowptr[node], end = rowptr[node + 1];
    int j = beg;
    for (; j + 4 <= end; j += 4) {
        int s0 = csr[j], s1 = csr[j + 1], s2 = csr[j + 2], s3 = csr[j + 3];
        float d0 = dis[s0], d1 = dis[s1], d2 = dis[s2], d3 = dis[s3];
        const float* r0 = X + (size_t)s0 * KIN;
        const float* r1 = X + (size_t)s1 * KIN;
        const float* r2 = X + (size_t)s2 * KIN;
        const float* r3 = X + (size_t)s3 * KIN;
        a1 += d0 * r0[lane] + d1 * r1[lane] + d2 * r2[lane] + d3 * r3[lane];
        if (hi) a2 += d0 * r0[lane + 64] + d1 * r1[lane + 64]
                    + d2 * r2[lane + 64] + d3 * r3[lane + 64];
    }
    for (; j < end; ++j) {
        int s = csr[j];
        float d = dis[s];
        const float* r = X + (size_t)s * KIN;
        a1 += d * r[lane];
        if (hi) a2 += d * r[lane + 64];
    }
    agg[(size_t)node * KIN + lane] = di * a1;
    if (hi) agg[(size_t)node * KIN + lane + 64] = di * a2;
}

// One wave per node over g2 (128 cols, pre-scaled rows). Lane owns 2 floats.
__global__ __launch_bounds__(256) void gather_h_kernel(
    const float* __restrict__ g, const int* __restrict__ rowptr,
    const int* __restrict__ csr, const float* __restrict__ dis,
    float* __restrict__ agg, int N)
{
    int node = blockIdx.x * 4 + (threadIdx.x >> 6);
    if (node >= N) return;
    int lane = threadIdx.x & 63;
    int beg = rowptr[node], end = rowptr[node + 1];

    float2 acc = *(const float2*)&g[(size_t)node * HID + lane * 2];  // self (pre-scaled)
    int j = beg;
    for (; j + 4 <= end; j += 4) {
        int s0 = csr[j], s1 = csr[j + 1], s2 = csr[j + 2], s3 = csr[j + 3];
        float2 v0 = *(const float2*)&g[(size_t)s0 * HID + lane * 2];
        float2 v1 = *(const float2*)&g[(size_t)s1 * HID + lane * 2];
        float2 v2 = *(const float2*)&g[(size_t)s2 * HID + lane * 2];
        float2 v3 = *(const float2*)&g[(size_t)s3 * HID + lane * 2];
        acc.x += v0.x + v1.x + v2.x + v3.x;
        acc.y += v0.y + v1.y + v2.y + v3.y;
    }
    for (; j < end; ++j) {
        int s = csr[j];
        float2 v = *(const float2*)&g[(size_t)s * HID + lane * 2];
        acc.x += v.x; acc.y += v.y;
    }
    float di = dis[node];
    float2 r; r.x = acc.x * di; r.y = acc.y * di;
    *(float2*)&agg[(size_t)node * HID + lane * 2] = r;
}

// One block = 32 node-rows; 4x4 micro-tile per thread out of LDS.
// SCALE_OUT: out = relu(a+b)*dis (layer 1 -> g2); else out = relu(a+b).
template<int K, bool SCALE_OUT>
__global__ __launch_bounds__(256, 2) void gemm_kernel(
    const float* __restrict__ X, const float* __restrict__ W,
    const float* __restrict__ bias, const float* __restrict__ dis,
    float* __restrict__ out, int N)
{
    __shared__ float Ws[K * HID];
    __shared__ float xs[K][32];
    const int tid = threadIdx.x;

    for (int i = tid; i < K * HID; i += 256) Ws[i] = W[i];

    const int node0 = blockIdx.x * 32;
    {
        const int nd = tid & 31;
        const int gn = node0 + nd;
        const bool ok = gn < N;
        for (int k = tid >> 5; k < K; k += 8)
            xs[k][nd] = ok ? X[(size_t)gn * K + k] : 0.0f;
    }
    __syncthreads();

    const int colq  = tid & 31;
    const int nodeq = tid >> 5;

    float a[4][4];
#pragma unroll
    for (int n = 0; n < 4; ++n)
#pragma unroll
        for (int c = 0; c < 4; ++c) a[n][c] = 0.0f;

    for (int k = 0; k < K; ++k) {
        float4 wv = *(const float4*)&Ws[k * HID + colq * 4];
        float4 xv = *(const float4*)&xs[k][nodeq * 4];
        float xn[4] = {xv.x, xv.y, xv.z, xv.w};
        float wc[4] = {wv.x, wv.y, wv.z, wv.w};
#pragma unroll
        for (int n = 0; n < 4; ++n)
#pragma unroll
            for (int c = 0; c < 4; ++c)
                a[n][c] = fmaf(xn[n], wc[c], a[n][c]);
    }

    float4 bb = *(const float4*)&bias[colq * 4];
#pragma unroll
    for (int n = 0; n < 4; ++n) {
        int node = node0 + nodeq * 4 + n;
        if (node < N) {
            float d = SCALE_OUT ? dis[node] : 1.0f;
            float4 r;
            r.x = fmaxf(a[n][0] + bb.x, 0.0f);
            r.y = fmaxf(a[n][1] + bb.y, 0.0f);
            r.z = fmaxf(a[n][2] + bb.z, 0.0f);
            r.w = fmaxf(a[n][3] + bb.w, 0.0f);
            if (SCALE_OUT) { r.x *= d; r.y *= d; r.z *= d; r.w *= d; }
            *(float4*)&out[(size_t)node * HID + colq * 4] = r;
        }
    }
}

__global__ void edge_copy_kernel(const int* __restrict__ e, float* __restrict__ out, int n) {
    int i = blockIdx.x * blockDim.x + threadIdx.x;
    if (i < n) out[i] = (float)e[i];
}

extern "C" void kernel_launch(void* const* d_in, const int* in_sizes, int n_in,
                              void* d_out, int out_size, void* d_ws, size_t ws_size,
                              hipStream_t stream) {
    const float* x  = (const float*)d_in[0];
    const int*   ei = (const int*)d_in[1];
    const float* W1 = (const float*)d_in[2];
    const float* b1 = (const float*)d_in[3];
    const float* W2 = (const float*)d_in[4];
    const float* b2 = (const float*)d_in[5];

    const int N = in_sizes[0] / KIN;  // 50000
    const int E = in_sizes[1] / 2;    // 800000
    const int* src = ei;
    const int* dst = ei + E;

    float* out  = (float*)d_out;
    float* outH = out;                      // [N,128]: agg2 staged here, then out
    float* outE = out + (size_t)N * HID;    // [2,E] edge_index as float

    // Workspace
    char* ws = (char*)d_ws;
    int*   degi   = (int*)ws;                 ws += (size_t)N * 4;
    int*   rowptr = (int*)ws;                 ws += (size_t)(N + 1) * 4;
    int*   cursor = (int*)ws;                 ws += (size_t)N * 4;
    int*   csr    = (int*)ws;                 ws += (size_t)E * 4;
    int*   bsum   = (int*)ws;                 ws += 64 * 4;
    int*   boff   = (int*)ws;                 ws += 64 * 4;
    float* dis    = (float*)ws;               ws += (size_t)N * 4;
    float* agg1   = (float*)ws;               ws += (size_t)N * KIN * 4;
    float* g2     = (float*)ws;               // N*128 floats

    const int nb = (N + 1023) / 1024;         // 49

    hipMemsetAsync(degi, 0, (size_t)N * 4, stream);
    degi_kernel<<<(E + 255) / 256, 256, 0, stream>>>(dst, degi, E);
    scanA_kernel<<<nb, 1024, 0, stream>>>(degi, bsum, N);
    scanB_kernel<<<1, 64, 0, stream>>>(bsum, boff, nb);
    scanC_kernel<<<nb, 1024, 0, stream>>>(degi, boff, rowptr, cursor, dis, N);
    csrfill_kernel<<<(E + 255) / 256, 256, 0, stream>>>(src, dst, cursor, csr, E);

    const int ngb = (N + 31) / 32;
    const int ngt = (N + 3) / 4;

    // Layer 1: gather X -> agg1, gemm -> g2 (relu * dis)
    gather_x_kernel<<<ngt, 256, 0, stream>>>(x, rowptr, csr, dis, agg1, N);
    gemm_kernel<KIN, true><<<ngb, 256, 0, stream>>>(agg1, W1, b1, dis, g2, N);

    // Layer 2: gather g2 -> agg2 (in outH), gemm in-place -> out
    gather_h_kernel<<<ngt, 256, 0, stream>>>(g2, rowptr, csr, dis, outH, N);
    gemm_kernel<HID, false><<<ngb, 256, 0, stream>>>(outH, W2, b2, dis, outH, N);

    edge_copy_kernel<<<(2 * E + 255) / 256, 256, 0, stream>>>(ei, outE, 2 * E);
}

// Round 4
// 363.714 us; speedup vs baseline: 4.1790x; 1.0376x over previous
//
#include <hip/hip_runtime.h>
#include <hip/hip_bf16.h>

// GCN 2-layer. Gather operands quantized to bf16 (halves cacheline-request
// count, the measured bottleneck); accumulation + GEMMs stay fp32.
//   Xh   = bf16(X) padded [N][96]                    (3 lines/row)
//   agg1 = dis_i*(dis_i*Xh_i + sum dis_s*Xh_s)       fp32 [N][96]
//   g2h  = bf16(relu(agg1@W1 + b1) * dis_i)          [N][128] (4 lines/row)
//   agg2 = dis_i*(g2h_i + sum g2h_s)                 fp32 (in d_out)
//   out  = relu(agg2@W2 + b2)
// CSR (by dst) gather -> no fp atomics, deterministic.

#define HID 128
#define KIN 89
#define KP 96   // padded input dim (bf16)

static __device__ inline float2 unpack_bf16(unsigned v) {
    union { unsigned u; float f; } lo, hi;
    lo.u = v << 16;
    hi.u = v & 0xFFFF0000u;
    return make_float2(lo.f, hi.f);
}

static __device__ inline unsigned pack_bf16(float a, float b) {
    __hip_bfloat162 h = __float22bfloat162_rn(make_float2(a, b));
    return *reinterpret_cast<unsigned*>(&h);
}

// Fused: copy edge_index -> out (as float) and count in-degrees from dst half.
__global__ void degi_edge_kernel(const int* __restrict__ ei, int* __restrict__ deg,
                                 float* __restrict__ outE, int E) {
    int i = blockIdx.x * blockDim.x + threadIdx.x;
    if (i < 2 * E) {
        int v = ei[i];
        outE[i] = (float)v;
        if (i >= E) atomicAdd(&deg[v], 1);
    }
}

// X fp32 [N][89] -> Xh bf16 [N][96] (pairs packed in uint), zero-padded.
__global__ void convx_kernel(const float* __restrict__ X, unsigned* __restrict__ Xh, int N) {
    int t = blockIdx.x * blockDim.x + threadIdx.x;
    if (t >= N * (KP / 2)) return;
    int n = t / (KP / 2);
    int c = t % (KP / 2);          // pair index: cols 2c, 2c+1
    const float* xr = X + (size_t)n * KIN;
    float a = (2 * c     < KIN) ? xr[2 * c]     : 0.0f;
    float b = (2 * c + 1 < KIN) ? xr[2 * c + 1] : 0.0f;
    Xh[(size_t)n * (KP / 2) + c] = pack_bf16(a, b);
}

// Phase A: per-block (1024 elems) sums of deg.
__global__ __launch_bounds__(1024) void scanA_kernel(
    const int* __restrict__ deg, int* __restrict__ bsum, int N)
{
    __shared__ int wsum[16];
    int tid = threadIdx.x, lane = tid & 63, wid = tid >> 6;
    int i = blockIdx.x * 1024 + tid;
    int v = (i < N) ? deg[i] : 0;
    int s = v;
#pragma unroll
    for (int off = 1; off < 64; off <<= 1) {
        int t = __shfl_up(s, off, 64);
        if (lane >= off) s += t;
    }
    if (lane == 63) wsum[wid] = s;
    __syncthreads();
    if (tid == 0) {
        int t = 0;
#pragma unroll
        for (int w = 0; w < 16; ++w) t += wsum[w];
        bsum[blockIdx.x] = t;
    }
}

// Phase B: exclusive scan of block sums (nb <= 64), one wave.
__global__ __launch_bounds__(64) void scanB_kernel(
    const int* __restrict__ bsum, int* __restrict__ boff, int nb)
{
    int lane = threadIdx.x;
    int v = (lane < nb) ? bsum[lane] : 0;
    int s = v;
#pragma unroll
    for (int off = 1; off < 64; off <<= 1) {
        int t = __shfl_up(s, off, 64);
        if (lane >= off) s += t;
    }
    if (lane < nb) boff[lane] = s - v;   // exclusive
}

// Phase C: full scan + write rowptr, cursor(=row start), dis.
__global__ __launch_bounds__(1024) void scanC_kernel(
    const int* __restrict__ deg, const int* __restrict__ boff,
    int* __restrict__ rowptr, int* __restrict__ cursor,
    float* __restrict__ dis, int N)
{
    __shared__ int wsum[16];
    int tid = threadIdx.x, lane = tid & 63, wid = tid >> 6;
    int i = blockIdx.x * 1024 + tid;
    int v = (i < N) ? deg[i] : 0;
    int s = v;
#pragma unroll
    for (int off = 1; off < 64; off <<= 1) {
        int t = __shfl_up(s, off, 64);
        if (lane >= off) s += t;
    }
    if (lane == 63) wsum[wid] = s;
    __syncthreads();
    if (wid == 0 && lane < 16) {
        int t = wsum[lane];
#pragma unroll
        for (int off = 1; off < 16; off <<= 1) {
            int u = __shfl_up(t, off, 16);
            if ((lane & 15) >= off) t += u;
        }
        wsum[lane] = t;
    }
    __syncthreads();
    int woff = wid ? wsum[wid - 1] : 0;
    int incl = boff[blockIdx.x] + woff + s;
    if (i < N) {
        rowptr[i + 1] = incl;
        cursor[i] = incl - v;
        dis[i] = rsqrtf(1.0f + (float)v);
    }
    if (i == 0) rowptr[0] = 0;
}

__global__ void csrfill_kernel(const int* __restrict__ src, const int* __restrict__ dst,
                               int* __restrict__ cursor, int* __restrict__ csr, int E)
{
    int e = blockIdx.x * blockDim.x + threadIdx.x;
    if (e < E) {
        int pos = atomicAdd(&cursor[dst[e]], 1);
        csr[pos] = src[e];
    }
}

// One wave per node over Xh bf16 [N][96]. Lane<48 owns cols 2*lane, 2*lane+1.
__global__ __launch_bounds__(256) void gather_x_kernel(
    const unsigned* __restrict__ Xh, const int* __restrict__ rowptr,
    const int* __restrict__ csr, const float* __restrict__ dis,
    float* __restrict__ agg, int N)
{
    int node = blockIdx.x * 4 + (threadIdx.x >> 6);
    if (node >= N) return;
    int lane = threadIdx.x & 63;
    bool act = lane < (KP / 2);
    float di = dis[node];

    float a0 = 0.0f, a1 = 0.0f;
    if (act) {
        float2 v = unpack_bf16(Xh[(size_t)node * (KP / 2) + lane]);
        a0 = di * v.x; a1 = di * v.y;
    }

    int beg = rowptr[node], end = rowptr[node + 1];
    int j = beg;
    for (; j + 4 <= end; j += 4) {
        int s0 = csr[j], s1 = csr[j + 1], s2 = csr[j + 2], s3 = csr[j + 3];
        float d0 = dis[s0], d1 = dis[s1], d2 = dis[s2], d3 = dis[s3];
        if (act) {
            float2 v0 = unpack_bf16(Xh[(size_t)s0 * (KP / 2) + lane]);
            float2 v1 = unpack_bf16(Xh[(size_t)s1 * (KP / 2) + lane]);
            float2 v2 = unpack_bf16(Xh[(size_t)s2 * (KP / 2) + lane]);
            float2 v3 = unpack_bf16(Xh[(size_t)s3 * (KP / 2) + lane]);
            a0 += d0 * v0.x + d1 * v1.x + d2 * v2.x + d3 * v3.x;
            a1 += d0 * v0.y + d1 * v1.y + d2 * v2.y + d3 * v3.y;
        }
    }
    for (; j < end; ++j) {
        int s = csr[j];
        float d = dis[s];
        if (act) {
            float2 v = unpack_bf16(Xh[(size_t)s * (KP / 2) + lane]);
            a0 += d * v.x; a1 += d * v.y;
        }
    }
    if (act) {
        float2 r; r.x = di * a0; r.y = di * a1;
        *(float2*)&agg[(size_t)node * KP + lane * 2] = r;
    }
}

// One wave per node over g2h bf16 [N][128]. Lane owns cols 2*lane, 2*lane+1.
__global__ __launch_bounds__(256) void gather_h_kernel(
    const unsigned* __restrict__ g, const int* __restrict__ rowptr,
    const int* __restrict__ csr, const float* __restrict__ dis,
    float* __restrict__ agg, int N)
{
    int node = blockIdx.x * 4 + (threadIdx.x >> 6);
    if (node >= N) return;
    int lane = threadIdx.x & 63;
    int beg = rowptr[node], end = rowptr[node + 1];

    float2 sv = unpack_bf16(g[(size_t)node * (HID / 2) + lane]);  // self (pre-scaled)
    float a0 = sv.x, a1 = sv.y;
    int j = beg;
    for (; j + 4 <= end; j += 4) {
        int s0 = csr[j], s1 = csr[j + 1], s2 = csr[j + 2], s3 = csr[j + 3];
        float2 v0 = unpack_bf16(g[(size_t)s0 * (HID / 2) + lane]);
        float2 v1 = unpack_bf16(g[(size_t)s1 * (HID / 2) + lane]);
        float2 v2 = unpack_bf16(g[(size_t)s2 * (HID / 2) + lane]);
        float2 v3 = unpack_bf16(g[(size_t)s3 * (HID / 2) + lane]);
        a0 += v0.x + v1.x + v2.x + v3.x;
        a1 += v0.y + v1.y + v2.y + v3.y;
    }
    for (; j < end; ++j) {
        int s = csr[j];
        float2 v = unpack_bf16(g[(size_t)s * (HID / 2) + lane]);
        a0 += v.x; a1 += v.y;
    }
    float di = dis[node];
    float2 r; r.x = a0 * di; r.y = a1 * di;
    *(float2*)&agg[(size_t)node * HID + lane * 2] = r;
}

// One block = 32 node-rows; 4x4 micro-tile per thread out of LDS.
// Layer 1: K=96 (pad W rows >=89 with 0), out = bf16(relu(a+b)*dis) -> g2h.
__global__ __launch_bounds__(256, 2) void gemm1_kernel(
    const float* __restrict__ X, const float* __restrict__ W,
    const float* __restrict__ bias, const float* __restrict__ dis,
    unsigned* __restrict__ outh, int N)
{
    __shared__ float Ws[KP * HID];
    __shared__ float xs[KP][32];
    const int tid = threadIdx.x;

    for (int i = tid; i < KP * HID; i += 256)
        Ws[i] = (i < KIN * HID) ? W[i] : 0.0f;

    const int node0 = blockIdx.x * 32;
    {
        const int nd = tid & 31;
        const int gn = node0 + nd;
        const bool ok = gn < N;
        for (int k = tid >> 5; k < KP; k += 8)
            xs[k][nd] = ok ? X[(size_t)gn * KP + k] : 0.0f;
    }
    __syncthreads();

    const int colq  = tid & 31;
    const int nodeq = tid >> 5;

    float a[4][4];
#pragma unroll
    for (int n = 0; n < 4; ++n)
#pragma unroll
        for (int c = 0; c < 4; ++c) a[n][c] = 0.0f;

    for (int k = 0; k < KP; ++k) {
        float4 wv = *(const float4*)&Ws[k * HID + colq * 4];
        float4 xv = *(const float4*)&xs[k][nodeq * 4];
        float xn[4] = {xv.x, xv.y, xv.z, xv.w};
        float wc[4] = {wv.x, wv.y, wv.z, wv.w};
#pragma unroll
        for (int n = 0; n < 4; ++n)
#pragma unroll
            for (int c = 0; c < 4; ++c)
                a[n][c] = fmaf(xn[n], wc[c], a[n][c]);
    }

    float4 bb = *(const float4*)&bias[colq * 4];
#pragma unroll
    for (int n = 0; n < 4; ++n) {
        int node = node0 + nodeq * 4 + n;
        if (node < N) {
            float d = dis[node];
            float r0 = fmaxf(a[n][0] + bb.x, 0.0f) * d;
            float r1 = fmaxf(a[n][1] + bb.y, 0.0f) * d;
            float r2 = fmaxf(a[n][2] + bb.z, 0.0f) * d;
            float r3 = fmaxf(a[n][3] + bb.w, 0.0f) * d;
            uint2 u; u.x = pack_bf16(r0, r1); u.y = pack_bf16(r2, r3);
            *(uint2*)&outh[(size_t)node * (HID / 2) + colq * 2] = u;
        }
    }
}

// Layer 2: K=128 fp32 in (agg2), fp32 out = relu(a+b), in-place safe per block.
__global__ __launch_bounds__(256, 2) void gemm2_kernel(
    const float* __restrict__ X, const float* __restrict__ W,
    const float* __restrict__ bias, float* __restrict__ out, int N)
{
    __shared__ float Ws[HID * HID];
    __shared__ float xs[HID][32];
    const int tid = threadIdx.x;

    for (int i = tid; i < HID * HID; i += 256) Ws[i] = W[i];

    const int node0 = blockIdx.x * 32;
    {
        const int nd = tid & 31;
        const int gn = node0 + nd;
        const bool ok = gn < N;
        for (int k = tid >> 5; k < HID; k += 8)
            xs[k][nd] = ok ? X[(size_t)gn * HID + k] : 0.0f;
    }
    __syncthreads();

    const int colq  = tid & 31;
    const int nodeq = tid >> 5;

    float a[4][4];
#pragma unroll
    for (int n = 0; n < 4; ++n)
#pragma unroll
        for (int c = 0; c < 4; ++c) a[n][c] = 0.0f;

    for (int k = 0; k < HID; ++k) {
        float4 wv = *(const float4*)&Ws[k * HID + colq * 4];
        float4 xv = *(const float4*)&xs[k][nodeq * 4];
        float xn[4] = {xv.x, xv.y, xv.z, xv.w};
        float wc[4] = {wv.x, wv.y, wv.z, wv.w};
#pragma unroll
        for (int n = 0; n < 4; ++n)
#pragma unroll
            for (int c = 0; c < 4; ++c)
                a[n][c] = fmaf(xn[n], wc[c], a[n][c]);
    }

    float4 bb = *(const float4*)&bias[colq * 4];
#pragma unroll
    for (int n = 0; n < 4; ++n) {
        int node = node0 + nodeq * 4 + n;
        if (node < N) {
            float4 r;
            r.x = fmaxf(a[n][0] + bb.x, 0.0f);
            r.y = fmaxf(a[n][1] + bb.y, 0.0f);
            r.z = fmaxf(a[n][2] + bb.z, 0.0f);
            r.w = fmaxf(a[n][3] + bb.w, 0.0f);
            *(float4*)&out[(size_t)node * HID + colq * 4] = r;
        }
    }
}

extern "C" void kernel_launch(void* const* d_in, const int* in_sizes, int n_in,
                              void* d_out, int out_size, void* d_ws, size_t ws_size,
                              hipStream_t stream) {
    const float* x  = (const float*)d_in[0];
    const int*   ei = (const int*)d_in[1];
    const float* W1 = (const float*)d_in[2];
    const float* b1 = (const float*)d_in[3];
    const float* W2 = (const float*)d_in[4];
    const float* b2 = (const float*)d_in[5];

    const int N = in_sizes[0] / KIN;  // 50000
    const int E = in_sizes[1] / 2;    // 800000
    const int* src = ei;
    const int* dst = ei + E;

    float* out  = (float*)d_out;
    float* outH = out;                      // [N,128]: agg2 staged here, then out
    float* outE = out + (size_t)N * HID;    // [2,E] edge_index as float

    // Workspace
    char* ws = (char*)d_ws;
    int*      degi   = (int*)ws;              ws += (size_t)N * 4;
    int*      rowptr = (int*)ws;              ws += (size_t)(N + 1) * 4;
    int*      cursor = (int*)ws;              ws += (size_t)N * 4;
    int*      csr    = (int*)ws;              ws += (size_t)E * 4;
    int*      bsum   = (int*)ws;              ws += 64 * 4;
    int*      boff   = (int*)ws;              ws += 64 * 4;
    float*    dis    = (float*)ws;            ws += (size_t)N * 4;
    unsigned* Xh     = (unsigned*)ws;         ws += (size_t)N * (KP / 2) * 4;
    float*    agg1   = (float*)ws;            ws += (size_t)N * KP * 4;
    unsigned* g2h    = (unsigned*)ws;         // N*64 uints (bf16 pairs)

    const int nb = (N + 1023) / 1024;         // 49

    hipMemsetAsync(degi, 0, (size_t)N * 4, stream);
    degi_edge_kernel<<<(2 * E + 255) / 256, 256, 0, stream>>>(ei, degi, outE, E);
    convx_kernel<<<(N * (KP / 2) + 255) / 256, 256, 0, stream>>>(x, Xh, N);
    scanA_kernel<<<nb, 1024, 0, stream>>>(degi, bsum, N);
    scanB_kernel<<<1, 64, 0, stream>>>(bsum, boff, nb);
    scanC_kernel<<<nb, 1024, 0, stream>>>(degi, boff, rowptr, cursor, dis, N);
    csrfill_kernel<<<(E + 255) / 256, 256, 0, stream>>>(src, dst, cursor, csr, E);

    const int ngb = (N + 31) / 32;
    const int ngt = (N + 3) / 4;

    // Layer 1
    gather_x_kernel<<<ngt, 256, 0, stream>>>(Xh, rowptr, csr, dis, agg1, N);
    gemm1_kernel<<<ngb, 256, 0, stream>>>(agg1, W1, b1, dis, g2h, N);

    // Layer 2
    gather_h_kernel<<<ngt, 256, 0, stream>>>(g2h, rowptr, csr, dis, outH, N);
    gemm2_kernel<<<ngb, 256, 0, stream>>>(outH, W2, b2, outH, N);
}

// Round 5
// 304.388 us; speedup vs baseline: 4.9934x; 1.1949x over previous
//
#include <hip/hip_runtime.h>
#include <hip/hip_bf16.h>

// GCN 2-layer, all-bf16 dataflow (fp32 accumulation everywhere):
//   Xh    = bf16(X) [N][96]                          (3 lines/row gather)
//   agg1h = bf16(dis_i*(dis_i*Xh_i + sum dis_s*Xh_s))  [N][96]
//   g2h   = bf16(relu(agg1h@W1t + b1) * dis_i)         [N][128]  (MFMA)
//   agg2h = bf16(dis_i*(g2h_i + sum g2h_s))            [N][128]
//   out   = relu(agg2h@W2t + b2)                       fp32 (MFMA)
// CSR (by dst) gather -> no fp atomics, deterministic.

#define HID 128
#define KIN 89
#define KP 96   // padded input dim

typedef __attribute__((ext_vector_type(8))) short bf16x8;
typedef __attribute__((ext_vector_type(4))) float f32x4;

static __device__ inline float2 unpack_bf16(unsigned v) {
    union { unsigned u; float f; } lo, hi;
    lo.u = v << 16;
    hi.u = v & 0xFFFF0000u;
    return make_float2(lo.f, hi.f);
}

static __device__ inline unsigned pack_bf16(float a, float b) {
    __hip_bfloat162 h = __float22bfloat162_rn(make_float2(a, b));
    return *reinterpret_cast<unsigned*>(&h);
}

static __device__ inline unsigned short f2bf(float v) {
    __hip_bfloat16 h = __float2bfloat16(v);
    return *reinterpret_cast<unsigned short*>(&h);
}

// Fused: copy edge_index -> out (as float) and count in-degrees from dst half.
__global__ void degi_edge_kernel(const int* __restrict__ ei, int* __restrict__ deg,
                                 float* __restrict__ outE, int E) {
    int i = blockIdx.x * blockDim.x + threadIdx.x;
    if (i < 2 * E) {
        int v = ei[i];
        outE[i] = (float)v;
        if (i >= E) atomicAdd(&deg[v], 1);
    }
}

// X fp32 [N][89] -> Xh bf16 [N][96] (pairs packed in uint), zero-padded.
__global__ void convx_kernel(const float* __restrict__ X, unsigned* __restrict__ Xh, int N) {
    int t = blockIdx.x * blockDim.x + threadIdx.x;
    if (t >= N * (KP / 2)) return;
    int n = t / (KP / 2);
    int c = t % (KP / 2);
    const float* xr = X + (size_t)n * KIN;
    float a = (2 * c     < KIN) ? xr[2 * c]     : 0.0f;
    float b = (2 * c + 1 < KIN) ? xr[2 * c + 1] : 0.0f;
    Xh[(size_t)n * (KP / 2) + c] = pack_bf16(a, b);
}

// W fp32 [K][128] -> Wt bf16 [128][KPA] (transposed, K zero-padded to KPA).
__global__ void transw_kernel(const float* __restrict__ W, unsigned short* __restrict__ Wt,
                              int K, int KPA) {
    int t = blockIdx.x * blockDim.x + threadIdx.x;
    if (t >= HID * KPA) return;
    int n = t / KPA, k = t % KPA;
    float v = (k < K) ? W[(size_t)k * HID + n] : 0.0f;
    Wt[t] = f2bf(v);
}

// Phase A: per-block (1024 elems) sums of deg.
__global__ __launch_bounds__(1024) void scanA_kernel(
    const int* __restrict__ deg, int* __restrict__ bsum, int N)
{
    __shared__ int wsum[16];
    int tid = threadIdx.x, lane = tid & 63, wid = tid >> 6;
    int i = blockIdx.x * 1024 + tid;
    int v = (i < N) ? deg[i] : 0;
    int s = v;
#pragma unroll
    for (int off = 1; off < 64; off <<= 1) {
        int t = __shfl_up(s, off, 64);
        if (lane >= off) s += t;
    }
    if (lane == 63) wsum[wid] = s;
    __syncthreads();
    if (tid == 0) {
        int t = 0;
#pragma unroll
        for (int w = 0; w < 16; ++w) t += wsum[w];
        bsum[blockIdx.x] = t;
    }
}

// Phase B: exclusive scan of block sums (nb <= 64), one wave.
__global__ __launch_bounds__(64) void scanB_kernel(
    const int* __restrict__ bsum, int* __restrict__ boff, int nb)
{
    int lane = threadIdx.x;
    int v = (lane < nb) ? bsum[lane] : 0;
    int s = v;
#pragma unroll
    for (int off = 1; off < 64; off <<= 1) {
        int t = __shfl_up(s, off, 64);
        if (lane >= off) s += t;
    }
    if (lane < nb) boff[lane] = s - v;
}

// Phase C: full scan + write rowptr, cursor(=row start), dis.
__global__ __launch_bounds__(1024) void scanC_kernel(
    const int* __restrict__ deg, const int* __restrict__ boff,
    int* __restrict__ rowptr, int* __restrict__ cursor,
    float* __restrict__ dis, int N)
{
    __shared__ int wsum[16];
    int tid = threadIdx.x, lane = tid & 63, wid = tid >> 6;
    int i = blockIdx.x * 1024 + tid;
    int v = (i < N) ? deg[i] : 0;
    int s = v;
#pragma unroll
    for (int off = 1; off < 64; off <<= 1) {
        int t = __shfl_up(s, off, 64);
        if (lane >= off) s += t;
    }
    if (lane == 63) wsum[wid] = s;
    __syncthreads();
    if (wid == 0 && lane < 16) {
        int t = wsum[lane];
#pragma unroll
        for (int off = 1; off < 16; off <<= 1) {
            int u = __shfl_up(t, off, 16);
            if ((lane & 15) >= off) t += u;
        }
        wsum[lane] = t;
    }
    __syncthreads();
    int woff = wid ? wsum[wid - 1] : 0;
    int incl = boff[blockIdx.x] + woff + s;
    if (i < N) {
        rowptr[i + 1] = incl;
        cursor[i] = incl - v;
        dis[i] = rsqrtf(1.0f + (float)v);
    }
    if (i == 0) rowptr[0] = 0;
}

__global__ void csrfill_kernel(const int* __restrict__ src, const int* __restrict__ dst,
                               int* __restrict__ cursor, int* __restrict__ csr, int E)
{
    int e = blockIdx.x * blockDim.x + threadIdx.x;
    if (e < E) {
        int pos = atomicAdd(&cursor[dst[e]], 1);
        csr[pos] = src[e];
    }
}

// One wave per node over Xh bf16 [N][96]. Lane<48 owns cols 2*lane, 2*lane+1.
// Writes agg1 as bf16 pairs.
__global__ __launch_bounds__(256) void gather_x_kernel(
    const unsigned* __restrict__ Xh, const int* __restrict__ rowptr,
    const int* __restrict__ csr, const float* __restrict__ dis,
    unsigned* __restrict__ aggh, int N)
{
    int node = blockIdx.x * 4 + (threadIdx.x >> 6);
    if (node >= N) return;
    int lane = threadIdx.x & 63;
    bool act = lane < (KP / 2);
    float di = dis[node];

    float a0 = 0.0f, a1 = 0.0f;
    if (act) {
        float2 v = unpack_bf16(Xh[(size_t)node * (KP / 2) + lane]);
        a0 = di * v.x; a1 = di * v.y;
    }

    int beg = rowptr[node], end = rowptr[node + 1];
    int j = beg;
    for (; j + 4 <= end; j += 4) {
        int s0 = csr[j], s1 = csr[j + 1], s2 = csr[j + 2], s3 = csr[j + 3];
        float d0 = dis[s0], d1 = dis[s1], d2 = dis[s2], d3 = dis[s3];
        if (act) {
            float2 v0 = unpack_bf16(Xh[(size_t)s0 * (KP / 2) + lane]);
            float2 v1 = unpack_bf16(Xh[(size_t)s1 * (KP / 2) + lane]);
            float2 v2 = unpack_bf16(Xh[(size_t)s2 * (KP / 2) + lane]);
            float2 v3 = unpack_bf16(Xh[(size_t)s3 * (KP / 2) + lane]);
            a0 += d0 * v0.x + d1 * v1.x + d2 * v2.x + d3 * v3.x;
            a1 += d0 * v0.y + d1 * v1.y + d2 * v2.y + d3 * v3.y;
        }
    }
    for (; j < end; ++j) {
        int s = csr[j];
        float d = dis[s];
        if (act) {
            float2 v = unpack_bf16(Xh[(size_t)s * (KP / 2) + lane]);
            a0 += d * v.x; a1 += d * v.y;
        }
    }
    if (act)
        aggh[(size_t)node * (KP / 2) + lane] = pack_bf16(di * a0, di * a1);
}

// One wave per node over g2h bf16 [N][128]. Writes agg2 as bf16 pairs.
__global__ __launch_bounds__(256) void gather_h_kernel(
    const unsigned* __restrict__ g, const int* __restrict__ rowptr,
    const int* __restrict__ csr, const float* __restrict__ dis,
    unsigned* __restrict__ aggh, int N)
{
    int node = blockIdx.x * 4 + (threadIdx.x >> 6);
    if (node >= N) return;
    int lane = threadIdx.x & 63;
    int beg = rowptr[node], end = rowptr[node + 1];

    float2 sv = unpack_bf16(g[(size_t)node * (HID / 2) + lane]);  // self (pre-scaled)
    float a0 = sv.x, a1 = sv.y;
    int j = beg;
    for (; j + 4 <= end; j += 4) {
        int s0 = csr[j], s1 = csr[j + 1], s2 = csr[j + 2], s3 = csr[j + 3];
        float2 v0 = unpack_bf16(g[(size_t)s0 * (HID / 2) + lane]);
        float2 v1 = unpack_bf16(g[(size_t)s1 * (HID / 2) + lane]);
        float2 v2 = unpack_bf16(g[(size_t)s2 * (HID / 2) + lane]);
        float2 v3 = unpack_bf16(g[(size_t)s3 * (HID / 2) + lane]);
        a0 += v0.x + v1.x + v2.x + v3.x;
        a1 += v0.y + v1.y + v2.y + v3.y;
    }
    for (; j < end; ++j) {
        int s = csr[j];
        float2 v = unpack_bf16(g[(size_t)s * (HID / 2) + lane]);
        a0 += v.x; a1 += v.y;
    }
    float di = dis[node];
    aggh[(size_t)node * (HID / 2) + lane] = pack_bf16(a0 * di, a1 * di);
}

// MFMA GEMM: out[N][128] = A[N][KPA](bf16) @ Wt[128][KPA]^T(bf16), no LDS.
// Block = 64 nodes (4 waves x 16), wave covers 128 cols as 8 16x16 tiles.
// A-frag: A[m=lane&15][k=quad*8+j] contiguous 16B. B-frag: Wt[n=lane&15][k].
// C/D: col=lane&15, row=quad*4+reg.  LAYER1: out=bf16(relu(a+b)*dis) else fp32 relu(a+b).
template<int KPA, bool LAYER1>
__global__ __launch_bounds__(256) void mfma_gemm_kernel(
    const unsigned short* __restrict__ A, const unsigned short* __restrict__ Wt,
    const float* __restrict__ bias, const float* __restrict__ dis,
    void* __restrict__ outp, int N)
{
    const int wave = threadIdx.x >> 6;
    const int lane = threadIdx.x & 63;
    const int m    = lane & 15;
    const int quad = lane >> 4;
    const int row0 = blockIdx.x * 64 + wave * 16;

    f32x4 acc[8];
#pragma unroll
    for (int t = 0; t < 8; ++t) acc[t] = (f32x4){0.0f, 0.0f, 0.0f, 0.0f};

    const int arow = min(row0 + m, N - 1);           // clamp: stores are guarded
    const unsigned short* arp = A + (size_t)arow * KPA;

#pragma unroll
    for (int c = 0; c < KPA / 32; ++c) {
        const int k0 = c * 32 + quad * 8;
        bf16x8 av = *(const bf16x8*)(arp + k0);
#pragma unroll
        for (int t = 0; t < 8; ++t) {
            bf16x8 bv = *(const bf16x8*)(Wt + (size_t)(t * 16 + m) * KPA + k0);
            acc[t] = __builtin_amdgcn_mfma_f32_16x16x32_bf16(av, bv, acc[t], 0, 0, 0);
        }
    }

    float dv[4];
#pragma unroll
    for (int r = 0; r < 4; ++r)
        dv[r] = LAYER1 ? dis[min(row0 + quad * 4 + r, N - 1)] : 1.0f;

#pragma unroll
    for (int t = 0; t < 8; ++t) {
        const int col = t * 16 + m;
        const float bb = bias[col];
#pragma unroll
        for (int r = 0; r < 4; ++r) {
            const int node = row0 + quad * 4 + r;
            if (node < N) {
                float v = fmaxf(acc[t][r] + bb, 0.0f);
                if (LAYER1)
                    ((unsigned short*)outp)[(size_t)node * HID + col] = f2bf(v * dv[r]);
                else
                    ((float*)outp)[(size_t)node * HID + col] = v;
            }
        }
    }
}

extern "C" void kernel_launch(void* const* d_in, const int* in_sizes, int n_in,
                              void* d_out, int out_size, void* d_ws, size_t ws_size,
                              hipStream_t stream) {
    const float* x  = (const float*)d_in[0];
    const int*   ei = (const int*)d_in[1];
    const float* W1 = (const float*)d_in[2];
    const float* b1 = (const float*)d_in[3];
    const float* W2 = (const float*)d_in[4];
    const float* b2 = (const float*)d_in[5];

    const int N = in_sizes[0] / KIN;  // 50000
    const int E = in_sizes[1] / 2;    // 800000
    const int* src = ei;
    const int* dst = ei + E;

    float* out  = (float*)d_out;
    float* outH = out;                      // [N,128] final fp32 output
    float* outE = out + (size_t)N * HID;    // [2,E] edge_index as float

    // Workspace (~49 MB)
    char* ws = (char*)d_ws;
    int*            degi   = (int*)ws;             ws += (size_t)N * 4;
    int*            rowptr = (int*)ws;             ws += (size_t)(N + 1) * 4 + 4;
    int*            cursor = (int*)ws;             ws += (size_t)N * 4;
    int*            csr    = (int*)ws;             ws += (size_t)E * 4;
    int*            bsum   = (int*)ws;             ws += 64 * 4;
    int*            boff   = (int*)ws;             ws += 64 * 4;
    float*          dis    = (float*)ws;           ws += (size_t)N * 4;
    unsigned*       Xh     = (unsigned*)ws;        ws += (size_t)N * (KP / 2) * 4;
    unsigned*       agg1h  = (unsigned*)ws;        ws += (size_t)N * (KP / 2) * 4;
    unsigned short* g2h    = (unsigned short*)ws;  ws += (size_t)N * HID * 2;
    unsigned short* agg2h  = (unsigned short*)ws;  ws += (size_t)N * HID * 2;
    unsigned short* W1t    = (unsigned short*)ws;  ws += (size_t)HID * KP * 2;
    unsigned short* W2t    = (unsigned short*)ws;  // HID*HID bf16

    const int nb = (N + 1023) / 1024;

    hipMemsetAsync(degi, 0, (size_t)N * 4, stream);
    degi_edge_kernel<<<(2 * E + 255) / 256, 256, 0, stream>>>(ei, degi, outE, E);
    convx_kernel<<<(N * (KP / 2) + 255) / 256, 256, 0, stream>>>(x, Xh, N);
    transw_kernel<<<(HID * KP + 255) / 256, 256, 0, stream>>>(W1, W1t, KIN, KP);
    transw_kernel<<<(HID * HID + 255) / 256, 256, 0, stream>>>(W2, W2t, HID, HID);
    scanA_kernel<<<nb, 1024, 0, stream>>>(degi, bsum, N);
    scanB_kernel<<<1, 64, 0, stream>>>(bsum, boff, nb);
    scanC_kernel<<<nb, 1024, 0, stream>>>(degi, boff, rowptr, cursor, dis, N);
    csrfill_kernel<<<(E + 255) / 256, 256, 0, stream>>>(src, dst, cursor, csr, E);

    const int ngt = (N + 3) / 4;
    const int ngm = (N + 63) / 64;

    // Layer 1
    gather_x_kernel<<<ngt, 256, 0, stream>>>(Xh, rowptr, csr, dis, agg1h, N);
    mfma_gemm_kernel<KP, true><<<ngm, 256, 0, stream>>>(
        (const unsigned short*)agg1h, W1t, b1, dis, g2h, N);

    // Layer 2
    gather_h_kernel<<<ngt, 256, 0, stream>>>((const unsigned*)g2h, rowptr, csr, dis,
                                             (unsigned*)agg2h, N);
    mfma_gemm_kernel<HID, false><<<ngm, 256, 0, stream>>>(
        agg2h, W2t, b2, dis, outH, N);
}

// Round 6
// 245.048 us; speedup vs baseline: 6.2027x; 1.2422x over previous
//
#include <hip/hip_runtime.h>
#include <hip/hip_bf16.h>

// GCN 2-layer, all-bf16 dataflow (fp32 accumulation), MFMA GEMMs, and a
// bucketed counting-sort CSR build (coalesced writes, no global fp atomics,
// no scattered-line write-back). Requires N < 65536 (src packed in 16 bits).
//
//   Xh    = bf16(X) [N][96]
//   agg1h = bf16(dis_i*(dis_i*Xh_i + sum dis_s*Xh_s))   [N][96]
//   g2h   = bf16(relu(agg1h@W1t + b1) * dis_i)          [N][128]  (MFMA)
//   agg2h = bf16(dis_i*(g2h_i + sum g2h_s))             [N][128]
//   out   = relu(agg2h@W2t + b2)                        fp32 (MFMA)

#define HID 128
#define KIN 89
#define KP 96     // padded input dim
#define BSH 8     // bucket = 256 nodes
#define BNODES 256
#define MAXBUCK 256   // LDS capacity for bucket histograms (NBUCK=196 here)
#define NPB 128       // partition blocks
#define P4CAP 6144    // staging capacity per bucket (mean ~4081, sd ~64)

typedef __attribute__((ext_vector_type(8))) short bf16x8;
typedef __attribute__((ext_vector_type(4))) float f32x4;

static __device__ inline float2 unpack_bf16(unsigned v) {
    union { unsigned u; float f; } lo, hi;
    lo.u = v << 16;
    hi.u = v & 0xFFFF0000u;
    return make_float2(lo.f, hi.f);
}

static __device__ inline unsigned pack_bf16(float a, float b) {
    __hip_bfloat162 h = __float22bfloat162_rn(make_float2(a, b));
    return *reinterpret_cast<unsigned*>(&h);
}

static __device__ inline unsigned short f2bf(float v) {
    __hip_bfloat16 h = __float2bfloat16(v);
    return *reinterpret_cast<unsigned short*>(&h);
}

// ---------------- misc prep ----------------

__global__ void edge_copy_kernel(const int* __restrict__ ei, float* __restrict__ outE, int n) {
    int i = blockIdx.x * blockDim.x + threadIdx.x;
    if (i < n) outE[i] = (float)ei[i];
}

// X fp32 [N][89] -> Xh bf16 [N][96] (pairs packed in uint), zero-padded.
__global__ void convx_kernel(const float* __restrict__ X, unsigned* __restrict__ Xh, int N) {
    int t = blockIdx.x * blockDim.x + threadIdx.x;
    if (t >= N * (KP / 2)) return;
    int n = t / (KP / 2);
    int c = t % (KP / 2);
    const float* xr = X + (size_t)n * KIN;
    float a = (2 * c     < KIN) ? xr[2 * c]     : 0.0f;
    float b = (2 * c + 1 < KIN) ? xr[2 * c + 1] : 0.0f;
    Xh[(size_t)n * (KP / 2) + c] = pack_bf16(a, b);
}

// W fp32 [K][128] -> Wt bf16 [128][KPA] (transposed, K zero-padded).
__global__ void transw_kernel(const float* __restrict__ W, unsigned short* __restrict__ Wt,
                              int K, int KPA) {
    int t = blockIdx.x * blockDim.x + threadIdx.x;
    if (t >= HID * KPA) return;
    int n = t / KPA, k = t % KPA;
    float v = (k < K) ? W[(size_t)k * HID + n] : 0.0f;
    Wt[t] = f2bf(v);
}

// ---------------- CSR build: bucketed counting sort ----------------

// P1: per partition-block histogram over buckets. histG[bucket*NPB + blk].
__global__ __launch_bounds__(256) void p1_hist_kernel(
    const int* __restrict__ dst, int* __restrict__ histG, int E, int nbuck)
{
    __shared__ int h[MAXBUCK];
    const int tid = threadIdx.x, blk = blockIdx.x;
    const int chunk = (E + NPB - 1) / NPB;
    const int beg = blk * chunk, end = min(beg + chunk, E);
    if (tid < nbuck) h[tid] = 0;
    __syncthreads();
    for (int i = beg + tid; i < end; i += 256)
        atomicAdd(&h[dst[i] >> BSH], 1);
    __syncthreads();
    if (tid < nbuck) histG[tid * NPB + blk] = h[tid];
}

// P2a: per-bucket exclusive scan of its NPB counts (in place) + bucket totals.
__global__ __launch_bounds__(NPB) void p2a_kernel(
    int* __restrict__ histG, int* __restrict__ totals)
{
    __shared__ int wsum[NPB / 64];
    const int b = blockIdx.x, tid = threadIdx.x, lane = tid & 63, wid = tid >> 6;
    int c = histG[b * NPB + tid];
    int s = c;
#pragma unroll
    for (int off = 1; off < 64; off <<= 1) {
        int t = __shfl_up(s, off, 64);
        if (lane >= off) s += t;
    }
    if (lane == 63) wsum[wid] = s;
    __syncthreads();
    if (tid == 0) {
        int a = 0;
#pragma unroll
        for (int w = 0; w < NPB / 64; ++w) { int t = wsum[w]; wsum[w] = a; a += t; }
    }
    __syncthreads();
    int excl = wsum[wid] + s - c;
    histG[b * NPB + tid] = excl;
    if (tid == NPB - 1) totals[b] = excl + c;
}

// P2b: exclusive scan of bucket totals -> base; also rowptr[N] = E.
__global__ __launch_bounds__(256) void p2b_kernel(
    const int* __restrict__ totals, int* __restrict__ base,
    int* __restrict__ rowptr, int nbuck, int N)
{
    __shared__ int wsum[4];
    const int tid = threadIdx.x, lane = tid & 63, wid = tid >> 6;
    int v = (tid < nbuck) ? totals[tid] : 0;
    int s = v;
#pragma unroll
    for (int off = 1; off < 64; off <<= 1) {
        int t = __shfl_up(s, off, 64);
        if (lane >= off) s += t;
    }
    if (lane == 63) wsum[wid] = s;
    __syncthreads();
    if (tid == 0) {
        int a = 0;
#pragma unroll
        for (int w = 0; w < 4; ++w) { int t = wsum[w]; wsum[w] = a; a += t; }
    }
    __syncthreads();
    int excl = wsum[wid] + s - v;
    base[tid] = excl;
    if (tid == nbuck - 1) rowptr[N] = excl + v;
}

// P3: partition edges into bucket-contiguous ebuf, packed (dstLocal<<16)|src.
__global__ __launch_bounds__(256) void p3_part_kernel(
    const int* __restrict__ src, const int* __restrict__ dst,
    const int* __restrict__ histG, const int* __restrict__ base,
    unsigned* __restrict__ ebuf, int E, int nbuck)
{
    __shared__ int cur[MAXBUCK];
    const int tid = threadIdx.x, blk = blockIdx.x;
    const int chunk = (E + NPB - 1) / NPB;
    const int beg = blk * chunk, end = min(beg + chunk, E);
    if (tid < nbuck) cur[tid] = base[tid] + histG[tid * NPB + blk];
    __syncthreads();
    for (int i = beg + tid; i < end; i += 256) {
        int d = dst[i];
        int b = d >> BSH;
        int pos = atomicAdd(&cur[b], 1);
        ebuf[pos] = ((unsigned)(d & (BNODES - 1)) << 16) | (unsigned)src[i];
    }
}

// P4: per bucket: count -> scan (emits rowptr+dis) -> LDS counting sort ->
// coalesced ushort csr write. Fallback to direct scatter on overflow.
__global__ __launch_bounds__(256) void p4_sort_kernel(
    const unsigned* __restrict__ ebuf, const int* __restrict__ base,
    const int* __restrict__ totals, unsigned short* __restrict__ csr,
    int* __restrict__ rowptr, float* __restrict__ dis, int N)
{
    __shared__ int counts[BNODES];
    __shared__ int cursor[BNODES];
    __shared__ int wsum[4];
    __shared__ unsigned short staging[P4CAP];
    const int b = blockIdx.x, tid = threadIdx.x, lane = tid & 63, wid = tid >> 6;
    const int gbase = base[b];
    const int cnt = totals[b];

    counts[tid] = 0;
    __syncthreads();
    for (int i = tid; i < cnt; i += 256)
        atomicAdd(&counts[ebuf[gbase + i] >> 16], 1);
    __syncthreads();

    // exclusive scan of 256 counts
    int c = counts[tid];
    int s = c;
#pragma unroll
    for (int off = 1; off < 64; off <<= 1) {
        int t = __shfl_up(s, off, 64);
        if (lane >= off) s += t;
    }
    if (lane == 63) wsum[wid] = s;
    __syncthreads();
    if (tid == 0) {
        int a = 0;
#pragma unroll
        for (int w = 0; w < 4; ++w) { int t = wsum[w]; wsum[w] = a; a += t; }
    }
    __syncthreads();
    int excl = wsum[wid] + s - c;
    cursor[tid] = excl;
    int node = b * BNODES + tid;
    if (node < N) {
        rowptr[node] = gbase + excl;
        dis[node] = rsqrtf(1.0f + (float)c);
    }
    __syncthreads();

    if (cnt <= P4CAP) {
        for (int i = tid; i < cnt; i += 256) {
            unsigned v = ebuf[gbase + i];
            int pos = atomicAdd(&cursor[v >> 16], 1);
            staging[pos] = (unsigned short)(v & 0xFFFFu);
        }
        __syncthreads();
        for (int i = tid; i < cnt; i += 256)
            csr[gbase + i] = staging[i];
    } else {
        for (int i = tid; i < cnt; i += 256) {
            unsigned v = ebuf[gbase + i];
            int pos = atomicAdd(&cursor[v >> 16], 1);
            csr[gbase + pos] = (unsigned short)(v & 0xFFFFu);
        }
    }
}

// ---------------- gathers ----------------

// One wave per node over Xh bf16 [N][96]. Lane<48 owns cols 2*lane, 2*lane+1.
__global__ __launch_bounds__(256) void gather_x_kernel(
    const unsigned* __restrict__ Xh, const int* __restrict__ rowptr,
    const unsigned short* __restrict__ csr, const float* __restrict__ dis,
    unsigned* __restrict__ aggh, int N)
{
    int node = blockIdx.x * 4 + (threadIdx.x >> 6);
    if (node >= N) return;
    int lane = threadIdx.x & 63;
    bool act = lane < (KP / 2);
    float di = dis[node];

    float a0 = 0.0f, a1 = 0.0f;
    if (act) {
        float2 v = unpack_bf16(Xh[(size_t)node * (KP / 2) + lane]);
        a0 = di * v.x; a1 = di * v.y;
    }

    int beg = rowptr[node], end = rowptr[node + 1];
    int j = beg;
    for (; j + 4 <= end; j += 4) {
        int s0 = csr[j], s1 = csr[j + 1], s2 = csr[j + 2], s3 = csr[j + 3];
        float d0 = dis[s0], d1 = dis[s1], d2 = dis[s2], d3 = dis[s3];
        if (act) {
            float2 v0 = unpack_bf16(Xh[(size_t)s0 * (KP / 2) + lane]);
            float2 v1 = unpack_bf16(Xh[(size_t)s1 * (KP / 2) + lane]);
            float2 v2 = unpack_bf16(Xh[(size_t)s2 * (KP / 2) + lane]);
            float2 v3 = unpack_bf16(Xh[(size_t)s3 * (KP / 2) + lane]);
            a0 += d0 * v0.x + d1 * v1.x + d2 * v2.x + d3 * v3.x;
            a1 += d0 * v0.y + d1 * v1.y + d2 * v2.y + d3 * v3.y;
        }
    }
    for (; j < end; ++j) {
        int s = csr[j];
        float d = dis[s];
        if (act) {
            float2 v = unpack_bf16(Xh[(size_t)s * (KP / 2) + lane]);
            a0 += d * v.x; a1 += d * v.y;
        }
    }
    if (act)
        aggh[(size_t)node * (KP / 2) + lane] = pack_bf16(di * a0, di * a1);
}

// One wave per node over g2h bf16 [N][128]. Writes agg2 as bf16 pairs.
__global__ __launch_bounds__(256) void gather_h_kernel(
    const unsigned* __restrict__ g, const int* __restrict__ rowptr,
    const unsigned short* __restrict__ csr, const float* __restrict__ dis,
    unsigned* __restrict__ aggh, int N)
{
    int node = blockIdx.x * 4 + (threadIdx.x >> 6);
    if (node >= N) return;
    int lane = threadIdx.x & 63;
    int beg = rowptr[node], end = rowptr[node + 1];

    float2 sv = unpack_bf16(g[(size_t)node * (HID / 2) + lane]);  // self (pre-scaled)
    float a0 = sv.x, a1 = sv.y;
    int j = beg;
    for (; j + 4 <= end; j += 4) {
        int s0 = csr[j], s1 = csr[j + 1], s2 = csr[j + 2], s3 = csr[j + 3];
        float2 v0 = unpack_bf16(g[(size_t)s0 * (HID / 2) + lane]);
        float2 v1 = unpack_bf16(g[(size_t)s1 * (HID / 2) + lane]);
        float2 v2 = unpack_bf16(g[(size_t)s2 * (HID / 2) + lane]);
        float2 v3 = unpack_bf16(g[(size_t)s3 * (HID / 2) + lane]);
        a0 += v0.x + v1.x + v2.x + v3.x;
        a1 += v0.y + v1.y + v2.y + v3.y;
    }
    for (; j < end; ++j) {
        int s = csr[j];
        float2 v = unpack_bf16(g[(size_t)s * (HID / 2) + lane]);
        a0 += v.x; a1 += v.y;
    }
    float di = dis[node];
    aggh[(size_t)node * (HID / 2) + lane] = pack_bf16(a0 * di, a1 * di);
}

// ---------------- MFMA GEMM (no LDS) ----------------
// Block = 64 nodes (4 waves x 16), wave covers 128 cols as 8 16x16 tiles.
template<int KPA, bool LAYER1>
__global__ __launch_bounds__(256) void mfma_gemm_kernel(
    const unsigned short* __restrict__ A, const unsigned short* __restrict__ Wt,
    const float* __restrict__ bias, const float* __restrict__ dis,
    void* __restrict__ outp, int N)
{
    const int wave = threadIdx.x >> 6;
    const int lane = threadIdx.x & 63;
    const int m    = lane & 15;
    const int quad = lane >> 4;
    const int row0 = blockIdx.x * 64 + wave * 16;

    f32x4 acc[8];
#pragma unroll
    for (int t = 0; t < 8; ++t) acc[t] = (f32x4){0.0f, 0.0f, 0.0f, 0.0f};

    const int arow = min(row0 + m, N - 1);           // clamp: stores are guarded
    const unsigned short* arp = A + (size_t)arow * KPA;

#pragma unroll
    for (int c = 0; c < KPA / 32; ++c) {
        const int k0 = c * 32 + quad * 8;
        bf16x8 av = *(const bf16x8*)(arp + k0);
#pragma unroll
        for (int t = 0; t < 8; ++t) {
            bf16x8 bv = *(const bf16x8*)(Wt + (size_t)(t * 16 + m) * KPA + k0);
            acc[t] = __builtin_amdgcn_mfma_f32_16x16x32_bf16(av, bv, acc[t], 0, 0, 0);
        }
    }

    float dv[4];
#pragma unroll
    for (int r = 0; r < 4; ++r)
        dv[r] = LAYER1 ? dis[min(row0 + quad * 4 + r, N - 1)] : 1.0f;

#pragma unroll
    for (int t = 0; t < 8; ++t) {
        const int col = t * 16 + m;
        const float bb = bias[col];
#pragma unroll
        for (int r = 0; r < 4; ++r) {
            const int node = row0 + quad * 4 + r;
            if (node < N) {
                float v = fmaxf(acc[t][r] + bb, 0.0f);
                if (LAYER1)
                    ((unsigned short*)outp)[(size_t)node * HID + col] = f2bf(v * dv[r]);
                else
                    ((float*)outp)[(size_t)node * HID + col] = v;
            }
        }
    }
}

// ---------------- launch ----------------

static inline char* wsal(char*& p, size_t n) {
    uintptr_t q = ((uintptr_t)p + 255) & ~(uintptr_t)255;
    char* r = (char*)q;
    p = r + n;
    return r;
}

extern "C" void kernel_launch(void* const* d_in, const int* in_sizes, int n_in,
                              void* d_out, int out_size, void* d_ws, size_t ws_size,
                              hipStream_t stream) {
    const float* x  = (const float*)d_in[0];
    const int*   ei = (const int*)d_in[1];
    const float* W1 = (const float*)d_in[2];
    const float* b1 = (const float*)d_in[3];
    const float* W2 = (const float*)d_in[4];
    const float* b2 = (const float*)d_in[5];

    const int N = in_sizes[0] / KIN;  // 50000  (< 65536 required)
    const int E = in_sizes[1] / 2;    // 800000
    const int* src = ei;
    const int* dst = ei + E;
    const int nbuck = (N + BNODES - 1) >> BSH;   // 196 (<= MAXBUCK)

    float* out  = (float*)d_out;
    float* outH = out;                      // [N,128] final fp32 output
    float* outE = out + (size_t)N * HID;    // [2,E] edge_index as float

    char* ws = (char*)d_ws;
    int*            histG  = (int*)wsal(ws, (size_t)MAXBUCK * NPB * 4);
    int*            totals = (int*)wsal(ws, MAXBUCK * 4);
    int*            base   = (int*)wsal(ws, MAXBUCK * 4);
    int*            rowptr = (int*)wsal(ws, (size_t)(N + 1) * 4);
    float*          dis    = (float*)wsal(ws, (size_t)N * 4);
    unsigned*       ebuf   = (unsigned*)wsal(ws, (size_t)E * 4);
    unsigned short* csr    = (unsigned short*)wsal(ws, (size_t)E * 2);
    unsigned*       Xh     = (unsigned*)wsal(ws, (size_t)N * (KP / 2) * 4);
    unsigned*       agg1h  = (unsigned*)wsal(ws, (size_t)N * (KP / 2) * 4);
    unsigned short* g2h    = (unsigned short*)wsal(ws, (size_t)N * HID * 2);
    unsigned short* agg2h  = (unsigned short*)wsal(ws, (size_t)N * HID * 2);
    unsigned short* W1t    = (unsigned short*)wsal(ws, (size_t)HID * KP * 2);
    unsigned short* W2t    = (unsigned short*)wsal(ws, (size_t)HID * HID * 2);

    // prep
    edge_copy_kernel<<<(2 * E + 255) / 256, 256, 0, stream>>>(ei, outE, 2 * E);
    convx_kernel<<<(N * (KP / 2) + 255) / 256, 256, 0, stream>>>(x, Xh, N);
    transw_kernel<<<(HID * KP + 255) / 256, 256, 0, stream>>>(W1, W1t, KIN, KP);
    transw_kernel<<<(HID * HID + 255) / 256, 256, 0, stream>>>(W2, W2t, HID, HID);

    // CSR build (also produces rowptr + dis)
    p1_hist_kernel<<<NPB, 256, 0, stream>>>(dst, histG, E, nbuck);
    p2a_kernel<<<nbuck, NPB, 0, stream>>>(histG, totals);
    p2b_kernel<<<1, 256, 0, stream>>>(totals, base, rowptr, nbuck, N);
    p3_part_kernel<<<NPB, 256, 0, stream>>>(src, dst, histG, base, ebuf, E, nbuck);
    p4_sort_kernel<<<nbuck, 256, 0, stream>>>(ebuf, base, totals, csr, rowptr, dis, N);

    const int ngt = (N + 3) / 4;
    const int ngm = (N + 63) / 64;

    // Layer 1
    gather_x_kernel<<<ngt, 256, 0, stream>>>(Xh, rowptr, csr, dis, agg1h, N);
    mfma_gemm_kernel<KP, true><<<ngm, 256, 0, stream>>>(
        (const unsigned short*)agg1h, W1t, b1, dis, g2h, N);

    // Layer 2
    gather_h_kernel<<<ngt, 256, 0, stream>>>((const unsigned*)g2h, rowptr, csr, dis,
                                             (unsigned*)agg2h, N);
    mfma_gemm_kernel<HID, false><<<ngm, 256, 0, stream>>>(
        agg2h, W2t, b2, dis, outH, N);
}

// Round 7
// 236.038 us; speedup vs baseline: 6.4394x; 1.0382x over previous
//
#include <hip/hip_runtime.h>
#include <hip/hip_bf16.h>

// GCN 2-layer, all-bf16 dataflow (fp32 accumulation), MFMA GEMMs with
// transposed-D epilogue (vectorized stores), bucketed counting-sort CSR
// build, 9 kernel launches total. Requires N < 65536.
//
//   Xh    = bf16(X) [N][96]
//   agg1h = bf16(dis_i*(dis_i*Xh_i + sum dis_s*Xh_s))   [N][96]
//   g2h   = bf16(relu(agg1h@W1t + b1) * dis_i)          [N][128]  (MFMA)
//   agg2h = bf16(dis_i*(g2h_i + sum g2h_s))             [N][128]
//   out   = relu(agg2h@W2t + b2)                        fp32 (MFMA)

#define HID 128
#define KIN 89
#define KP 96     // padded input dim
#define BSH 8     // bucket = 256 nodes
#define BNODES 256
#define MAXBUCK 256
#define NPB 128       // partition blocks
#define P4CAP 6144    // staging capacity per bucket (mean ~4081)

typedef __attribute__((ext_vector_type(8))) short bf16x8;
typedef __attribute__((ext_vector_type(4))) float f32x4;

static __device__ inline float2 unpack_bf16(unsigned v) {
    union { unsigned u; float f; } lo, hi;
    lo.u = v << 16;
    hi.u = v & 0xFFFF0000u;
    return make_float2(lo.f, hi.f);
}

static __device__ inline unsigned pack_bf16(float a, float b) {
    __hip_bfloat162 h = __float22bfloat162_rn(make_float2(a, b));
    return *reinterpret_cast<unsigned*>(&h);
}

static __device__ inline unsigned short f2bf(float v) {
    __hip_bfloat16 h = __float2bfloat16(v);
    return *reinterpret_cast<unsigned short*>(&h);
}

// ---------------- fused prep: edge copy + convx + transw1 + transw2 --------

__global__ __launch_bounds__(256) void prep_kernel(
    const int* __restrict__ ei, float* __restrict__ outE,
    const float* __restrict__ X, unsigned* __restrict__ Xh,
    const float* __restrict__ W1, unsigned short* __restrict__ W1t,
    const float* __restrict__ W2, unsigned short* __restrict__ W2t,
    int N, int E)
{
    const int nA = 2 * E;
    const int nB = N * (KP / 2);
    const int nC = HID * KP;
    const int nD = HID * HID;
    int i = blockIdx.x * 256 + threadIdx.x;
    if (i < nA) {
        outE[i] = (float)ei[i];
        return;
    }
    i -= nA;
    if (i < nB) {
        int n = i / (KP / 2);
        int c = i % (KP / 2);
        const float* xr = X + (size_t)n * KIN;
        float a = (2 * c     < KIN) ? xr[2 * c]     : 0.0f;
        float b = (2 * c + 1 < KIN) ? xr[2 * c + 1] : 0.0f;
        Xh[(size_t)n * (KP / 2) + c] = pack_bf16(a, b);
        return;
    }
    i -= nB;
    if (i < nC) {
        int n = i / KP, k = i % KP;
        float v = (k < KIN) ? W1[(size_t)k * HID + n] : 0.0f;
        W1t[i] = f2bf(v);
        return;
    }
    i -= nC;
    if (i < nD) {
        int n = i / HID, k = i % HID;
        W2t[i] = f2bf(W2[(size_t)k * HID + n]);
    }
}

// ---------------- CSR build: bucketed counting sort ----------------

// P1: per partition-block histogram over buckets. histG[bucket*NPB + blk].
__global__ __launch_bounds__(256) void p1_hist_kernel(
    const int* __restrict__ dst, int* __restrict__ histG, int E, int nbuck)
{
    __shared__ int h[MAXBUCK];
    const int tid = threadIdx.x, blk = blockIdx.x;
    const int chunk = (E + NPB - 1) / NPB;
    const int beg = blk * chunk, end = min(beg + chunk, E);
    if (tid < nbuck) h[tid] = 0;
    __syncthreads();
    for (int i = beg + tid; i < end; i += 256)
        atomicAdd(&h[dst[i] >> BSH], 1);
    __syncthreads();
    if (tid < nbuck) histG[tid * NPB + blk] = h[tid];
}

// P2a: per-bucket exclusive scan of its NPB counts (in place) + bucket totals.
__global__ __launch_bounds__(NPB) void p2a_kernel(
    int* __restrict__ histG, int* __restrict__ totals)
{
    __shared__ int wsum[NPB / 64];
    const int b = blockIdx.x, tid = threadIdx.x, lane = tid & 63, wid = tid >> 6;
    int c = histG[b * NPB + tid];
    int s = c;
#pragma unroll
    for (int off = 1; off < 64; off <<= 1) {
        int t = __shfl_up(s, off, 64);
        if (lane >= off) s += t;
    }
    if (lane == 63) wsum[wid] = s;
    __syncthreads();
    if (tid == 0) {
        int a = 0;
#pragma unroll
        for (int w = 0; w < NPB / 64; ++w) { int t = wsum[w]; wsum[w] = a; a += t; }
    }
    __syncthreads();
    int excl = wsum[wid] + s - c;
    histG[b * NPB + tid] = excl;
    if (tid == NPB - 1) totals[b] = excl + c;
}

// In-block exclusive scan of totals[0..nbuck) -> sexcl[tid] (256 threads).
static __device__ inline void scan_totals(const int* __restrict__ totals,
                                          int* __restrict__ sexcl,
                                          int* __restrict__ wsum,
                                          int nbuck, int tid)
{
    const int lane = tid & 63, wid = tid >> 6;
    int v = (tid < nbuck) ? totals[tid] : 0;
    int s = v;
#pragma unroll
    for (int off = 1; off < 64; off <<= 1) {
        int t = __shfl_up(s, off, 64);
        if (lane >= off) s += t;
    }
    if (lane == 63) wsum[wid] = s;
    __syncthreads();
    if (tid == 0) {
        int a = 0;
#pragma unroll
        for (int w = 0; w < 4; ++w) { int t = wsum[w]; wsum[w] = a; a += t; }
    }
    __syncthreads();
    sexcl[tid] = wsum[wid] + s - v;
}

// P3: partition edges into bucket-contiguous ebuf, packed (dstLocal<<16)|src.
__global__ __launch_bounds__(256) void p3_part_kernel(
    const int* __restrict__ src, const int* __restrict__ dst,
    const int* __restrict__ histG, const int* __restrict__ totals,
    unsigned* __restrict__ ebuf, int E, int nbuck)
{
    __shared__ int cur[MAXBUCK];
    __shared__ int wsum[4];
    const int tid = threadIdx.x, blk = blockIdx.x;
    scan_totals(totals, cur, wsum, nbuck, tid);   // cur[tid] = base[tid]
    __syncthreads();
    if (tid < nbuck) cur[tid] += histG[tid * NPB + blk];
    const int chunk = (E + NPB - 1) / NPB;
    const int beg = blk * chunk, end = min(beg + chunk, E);
    __syncthreads();
    for (int i = beg + tid; i < end; i += 256) {
        int d = dst[i];
        int b = d >> BSH;
        int pos = atomicAdd(&cur[b], 1);
        ebuf[pos] = ((unsigned)(d & (BNODES - 1)) << 16) | (unsigned)src[i];
    }
}

// P4: per bucket: count -> scan (emits rowptr+dis) -> LDS counting sort ->
// coalesced ushort csr write. Fallback to direct scatter on overflow.
__global__ __launch_bounds__(256) void p4_sort_kernel(
    const unsigned* __restrict__ ebuf, const int* __restrict__ totals,
    unsigned short* __restrict__ csr, int* __restrict__ rowptr,
    float* __restrict__ dis, int N, int E, int nbuck)
{
    __shared__ int counts[BNODES];
    __shared__ int cursor[BNODES];
    __shared__ int sbase[MAXBUCK];
    __shared__ int wsum[4];
    __shared__ unsigned short staging[P4CAP];
    const int b = blockIdx.x, tid = threadIdx.x, lane = tid & 63, wid = tid >> 6;

    scan_totals(totals, sbase, wsum, nbuck, tid);
    __syncthreads();
    const int gbase = sbase[b];
    const int cnt = totals[b];

    counts[tid] = 0;
    __syncthreads();
    for (int i = tid; i < cnt; i += 256)
        atomicAdd(&counts[ebuf[gbase + i] >> 16], 1);
    __syncthreads();

    // exclusive scan of 256 counts
    int c = counts[tid];
    int s = c;
#pragma unroll
    for (int off = 1; off < 64; off <<= 1) {
        int t = __shfl_up(s, off, 64);
        if (lane >= off) s += t;
    }
    if (lane == 63) wsum[wid] = s;
    __syncthreads();
    if (tid == 0) {
        int a = 0;
#pragma unroll
        for (int w = 0; w < 4; ++w) { int t = wsum[w]; wsum[w] = a; a += t; }
    }
    __syncthreads();
    int excl = wsum[wid] + s - c;
    cursor[tid] = excl;
    int node = b * BNODES + tid;
    if (node < N) {
        rowptr[node] = gbase + excl;
        dis[node] = rsqrtf(1.0f + (float)c);
    }
    if (b == 0 && tid == 0) rowptr[N] = E;
    __syncthreads();

    if (cnt <= P4CAP) {
        for (int i = tid; i < cnt; i += 256) {
            unsigned v = ebuf[gbase + i];
            int pos = atomicAdd(&cursor[v >> 16], 1);
            staging[pos] = (unsigned short)(v & 0xFFFFu);
        }
        __syncthreads();
        for (int i = tid; i < cnt; i += 256)
            csr[gbase + i] = staging[i];
    } else {
        for (int i = tid; i < cnt; i += 256) {
            unsigned v = ebuf[gbase + i];
            int pos = atomicAdd(&cursor[v >> 16], 1);
            csr[gbase + pos] = (unsigned short)(v & 0xFFFFu);
        }
    }
}

// ---------------- gathers ----------------

// One wave per node over Xh bf16 [N][96]. Lane<48 owns cols 2*lane, 2*lane+1.
__global__ __launch_bounds__(256) void gather_x_kernel(
    const unsigned* __restrict__ Xh, const int* __restrict__ rowptr,
    const unsigned short* __restrict__ csr, const float* __restrict__ dis,
    unsigned* __restrict__ aggh, int N)
{
    int node = blockIdx.x * 4 + (threadIdx.x >> 6);
    if (node >= N) return;
    int lane = threadIdx.x & 63;
    bool act = lane < (KP / 2);
    float di = dis[node];

    float a0 = 0.0f, a1 = 0.0f;
    if (act) {
        float2 v = unpack_bf16(Xh[(size_t)node * (KP / 2) + lane]);
        a0 = di * v.x; a1 = di * v.y;
    }

    int beg = rowptr[node], end = rowptr[node + 1];
    int j = beg;
    for (; j + 4 <= end; j += 4) {
        int s0 = csr[j], s1 = csr[j + 1], s2 = csr[j + 2], s3 = csr[j + 3];
        float d0 = dis[s0], d1 = dis[s1], d2 = dis[s2], d3 = dis[s3];
        if (act) {
            float2 v0 = unpack_bf16(Xh[(size_t)s0 * (KP / 2) + lane]);
            float2 v1 = unpack_bf16(Xh[(size_t)s1 * (KP / 2) + lane]);
            float2 v2 = unpack_bf16(Xh[(size_t)s2 * (KP / 2) + lane]);
            float2 v3 = unpack_bf16(Xh[(size_t)s3 * (KP / 2) + lane]);
            a0 += d0 * v0.x + d1 * v1.x + d2 * v2.x + d3 * v3.x;
            a1 += d0 * v0.y + d1 * v1.y + d2 * v2.y + d3 * v3.y;
        }
    }
    for (; j < end; ++j) {
        int s = csr[j];
        float d = dis[s];
        if (act) {
            float2 v = unpack_bf16(Xh[(size_t)s * (KP / 2) + lane]);
            a0 += d * v.x; a1 += d * v.y;
        }
    }
    if (act)
        aggh[(size_t)node * (KP / 2) + lane] = pack_bf16(di * a0, di * a1);
}

// One wave per node over g2h bf16 [N][128]. Writes agg2 as bf16 pairs.
__global__ __launch_bounds__(256) void gather_h_kernel(
    const unsigned* __restrict__ g, const int* __restrict__ rowptr,
    const unsigned short* __restrict__ csr, const float* __restrict__ dis,
    unsigned* __restrict__ aggh, int N)
{
    int node = blockIdx.x * 4 + (threadIdx.x >> 6);
    if (node >= N) return;
    int lane = threadIdx.x & 63;
    int beg = rowptr[node], end = rowptr[node + 1];

    float2 sv = unpack_bf16(g[(size_t)node * (HID / 2) + lane]);  // self (pre-scaled)
    float a0 = sv.x, a1 = sv.y;
    int j = beg;
    for (; j + 4 <= end; j += 4) {
        int s0 = csr[j], s1 = csr[j + 1], s2 = csr[j + 2], s3 = csr[j + 3];
        float2 v0 = unpack_bf16(g[(size_t)s0 * (HID / 2) + lane]);
        float2 v1 = unpack_bf16(g[(size_t)s1 * (HID / 2) + lane]);
        float2 v2 = unpack_bf16(g[(size_t)s2 * (HID / 2) + lane]);
        float2 v3 = unpack_bf16(g[(size_t)s3 * (HID / 2) + lane]);
        a0 += v0.x + v1.x + v2.x + v3.x;
        a1 += v0.y + v1.y + v2.y + v3.y;
    }
    for (; j < end; ++j) {
        int s = csr[j];
        float2 v = unpack_bf16(g[(size_t)s * (HID / 2) + lane]);
        a0 += v.x; a1 += v.y;
    }
    float di = dis[node];
    aggh[(size_t)node * (HID / 2) + lane] = pack_bf16(a0 * di, a1 * di);
}

// ---------------- MFMA GEMM (no LDS, transposed-D epilogue) ----------------
// Block = 64 nodes (4 waves x 16), wave covers 128 cols as 8 16x16 tiles.
// Operands swapped vs classic: mfma(Wt-frag, node-frag) -> D[outcol][node].
// Lane (m=lane&15, quad) holds node=row0+m, cols t*16+quad*4+{0..3} ->
// vectorized 8B (bf16) / 16B (fp32) stores.
template<int KPA, bool LAYER1>
__global__ __launch_bounds__(256) void mfma_gemm_kernel(
    const unsigned short* __restrict__ A, const unsigned short* __restrict__ Wt,
    const float* __restrict__ bias, const float* __restrict__ dis,
    void* __restrict__ outp, int N)
{
    const int wave = threadIdx.x >> 6;
    const int lane = threadIdx.x & 63;
    const int m    = lane & 15;
    const int quad = lane >> 4;
    const int row0 = blockIdx.x * 64 + wave * 16;
    const int node = row0 + m;

    f32x4 acc[8];
#pragma unroll
    for (int t = 0; t < 8; ++t) acc[t] = (f32x4){0.0f, 0.0f, 0.0f, 0.0f};

    const int arow = min(node, N - 1);           // clamp: stores are guarded
    const unsigned short* arp = A + (size_t)arow * KPA;

#pragma unroll
    for (int c = 0; c < KPA / 32; ++c) {
        const int k0 = c * 32 + quad * 8;
        bf16x8 nv = *(const bf16x8*)(arp + k0);                      // B-frag
#pragma unroll
        for (int t = 0; t < 8; ++t) {
            bf16x8 wv = *(const bf16x8*)(Wt + (size_t)(t * 16 + m) * KPA + k0);  // A-frag
            acc[t] = __builtin_amdgcn_mfma_f32_16x16x32_bf16(wv, nv, acc[t], 0, 0, 0);
        }
    }

    if (node < N) {
        const float dv = LAYER1 ? dis[node] : 1.0f;
#pragma unroll
        for (int t = 0; t < 8; ++t) {
            const int col0 = t * 16 + quad * 4;
            float4 bb = *(const float4*)&bias[col0];
            float r0 = fmaxf(acc[t][0] + bb.x, 0.0f);
            float r1 = fmaxf(acc[t][1] + bb.y, 0.0f);
            float r2 = fmaxf(acc[t][2] + bb.z, 0.0f);
            float r3 = fmaxf(acc[t][3] + bb.w, 0.0f);
            if (LAYER1) {
                uint2 u;
                u.x = pack_bf16(r0 * dv, r1 * dv);
                u.y = pack_bf16(r2 * dv, r3 * dv);
                *(uint2*)((unsigned short*)outp + (size_t)node * HID + col0) = u;
            } else {
                float4 r = make_float4(r0, r1, r2, r3);
                *(float4*)((float*)outp + (size_t)node * HID + col0) = r;
            }
        }
    }
}

// ---------------- launch ----------------

static inline char* wsal(char*& p, size_t n) {
    uintptr_t q = ((uintptr_t)p + 255) & ~(uintptr_t)255;
    char* r = (char*)q;
    p = r + n;
    return r;
}

extern "C" void kernel_launch(void* const* d_in, const int* in_sizes, int n_in,
                              void* d_out, int out_size, void* d_ws, size_t ws_size,
                              hipStream_t stream) {
    const float* x  = (const float*)d_in[0];
    const int*   ei = (const int*)d_in[1];
    const float* W1 = (const float*)d_in[2];
    const float* b1 = (const float*)d_in[3];
    const float* W2 = (const float*)d_in[4];
    const float* b2 = (const float*)d_in[5];

    const int N = in_sizes[0] / KIN;  // 50000  (< 65536 required)
    const int E = in_sizes[1] / 2;    // 800000
    const int* src = ei;
    const int* dst = ei + E;
    const int nbuck = (N + BNODES - 1) >> BSH;   // 196 (<= MAXBUCK)

    float* out  = (float*)d_out;
    float* outH = out;                      // [N,128] final fp32 output
    float* outE = out + (size_t)N * HID;    // [2,E] edge_index as float

    char* ws = (char*)d_ws;
    int*            histG  = (int*)wsal(ws, (size_t)MAXBUCK * NPB * 4);
    int*            totals = (int*)wsal(ws, MAXBUCK * 4);
    int*            rowptr = (int*)wsal(ws, (size_t)(N + 1) * 4);
    float*          dis    = (float*)wsal(ws, (size_t)N * 4);
    unsigned*       ebuf   = (unsigned*)wsal(ws, (size_t)E * 4);
    unsigned short* csr    = (unsigned short*)wsal(ws, (size_t)E * 2);
    unsigned*       Xh     = (unsigned*)wsal(ws, (size_t)N * (KP / 2) * 4);
    unsigned*       agg1h  = (unsigned*)wsal(ws, (size_t)N * (KP / 2) * 4);
    unsigned short* g2h    = (unsigned short*)wsal(ws, (size_t)N * HID * 2);
    unsigned short* agg2h  = (unsigned short*)wsal(ws, (size_t)N * HID * 2);
    unsigned short* W1t    = (unsigned short*)wsal(ws, (size_t)HID * KP * 2);
    unsigned short* W2t    = (unsigned short*)wsal(ws, (size_t)HID * HID * 2);

    // fused prep (edge copy + bf16 convert + both weight transposes)
    {
        const int total = 2 * E + N * (KP / 2) + HID * KP + HID * HID;
        prep_kernel<<<(total + 255) / 256, 256, 0, stream>>>(
            ei, outE, x, Xh, W1, W1t, W2, W2t, N, E);
    }

    // CSR build (also produces rowptr + dis)
    p1_hist_kernel<<<NPB, 256, 0, stream>>>(dst, histG, E, nbuck);
    p2a_kernel<<<nbuck, NPB, 0, stream>>>(histG, totals);
    p3_part_kernel<<<NPB, 256, 0, stream>>>(src, dst, histG, totals, ebuf, E, nbuck);
    p4_sort_kernel<<<nbuck, 256, 0, stream>>>(ebuf, totals, csr, rowptr, dis, N, E, nbuck);

    const int ngt = (N + 3) / 4;
    const int ngm = (N + 63) / 64;

    // Layer 1
    gather_x_kernel<<<ngt, 256, 0, stream>>>(Xh, rowptr, csr, dis, agg1h, N);
    mfma_gemm_kernel<KP, true><<<ngm, 256, 0, stream>>>(
        (const unsigned short*)agg1h, W1t, b1, dis, g2h, N);

    // Layer 2
    gather_h_kernel<<<ngt, 256, 0, stream>>>((const unsigned*)g2h, rowptr, csr, dis,
                                             (unsigned*)agg2h, N);
    mfma_gemm_kernel<HID, false><<<ngm, 256, 0, stream>>>(
        agg2h, W2t, b2, dis, outH, N);
}